// Round 8
// baseline (323.942 us; speedup 1.0000x reference)
//
#include <hip/hip_runtime.h>

// RA_MLA_Attention — MI355X (gfx950). Round 14.
// B=1, T=2048, E=2048, H=16, D=128, L=64, RA_WINDOW=64, RA_ALPHA=0.5
//
// Round-14 changes (k_attn only; r12 GEMMs + rest byte-identical):
//   * k_attn rewritten with NO K/V staging (K=256KB, V/head=512KB both
//     L2-fit -> staging was pure overhead; m169 precedent +26%).
//     1 wave per block (64 thr, 5120 blocks), K/V fragments loaded
//     coalesced global->register, ZERO barriers, Ps = 2KB wave scratch.
//     Waves fully independent -> TLP hides L2 latency; wave-granular
//     blocks fix the work-imbalance tail.
//   * r13 history: staging latency/barriers/residency all exonerated
//     (43-47us across 4 structural variants); the 4x duplicated LDS
//     reads + lockstep coupling were the remaining suspect.

#define T_ 2048
#define E_ 2048
#define H_ 16
#define D_ 128
#define L_ 64
#define NQ 1152            // fused qkv GEMM N (1024 ql | 64 k | 64 v)

typedef float  floatx4 __attribute__((ext_vector_type(4)));
typedef __bf16 bf16x8  __attribute__((ext_vector_type(8)));

__device__ __forceinline__ ushort f2b(float x){           // fp32 -> bf16 bits, RNE
  unsigned int u = __float_as_uint(x);
  u = (u + 0x7fffu + ((u >> 16) & 1u)) >> 16;
  return (ushort)u;
}
__device__ __forceinline__ float blo(unsigned int u){ return __uint_as_float(u << 16); }
__device__ __forceinline__ float bhi(unsigned int u){ return __uint_as_float(u & 0xffff0000u); }

__device__ __forceinline__ void glds16(const ushort* g, ushort* l){
#if __has_builtin(__builtin_amdgcn_global_load_lds)
  __builtin_amdgcn_global_load_lds((const __attribute__((address_space(1))) void*)g,
                                   (__attribute__((address_space(3))) void*)l, 16, 0, 0);
#else
  *(uint4*)l = *(const uint4*)g;
#endif
}

// ---------------- fused fp32 -> bf16 convert (4 tensors, 1 launch) ----------
__global__ __launch_bounds__(256)
void k_f2b4(const float* __restrict__ a, ushort* __restrict__ oa,
            const float* __restrict__ b, ushort* __restrict__ ob,
            const float* __restrict__ c, ushort* __restrict__ oc,
            const float* __restrict__ d, ushort* __restrict__ od){
  int bid = blockIdx.x; const float* src; ushort* dst; int base;
  if (bid < 4096){ src=a; dst=oa; base=bid; }
  else if (bid < 8192){ src=b; dst=ob; base=bid-4096; }
  else if (bid < 8320){ src=c; dst=oc; base=bid-8192; }
  else { src=d; dst=od; base=bid-8320; }
  int i = (base*256 + (int)threadIdx.x)*4;
  float4 v = *(const float4*)(src + i);
  ushort4 o; o.x=f2b(v.x); o.y=f2b(v.y); o.z=f2b(v.z); o.w=f2b(v.w);
  *(ushort4*)(dst + i) = o;
}

// ---------------- fold q_to_latent into Wq:  Wql[(h,l),e] (rows of Wqkvb) ----
__global__ __launch_bounds__(128)
void k_prep_wql(const float* __restrict__ Wq, const float* __restrict__ q2l,
                ushort* __restrict__ Wql){
  const int h = blockIdx.z, lh = blockIdx.y;            // l half: lh*32..lh*32+31
  const int e = blockIdx.x*128 + threadIdx.x;
  const float* qb = q2l + (size_t)h*D_*L_ + lh*32;
  float acc[32];
  #pragma unroll
  for (int i=0;i<32;++i) acc[i]=0.f;
  for (int d=0; d<128; ++d){
    float wv = Wq[(size_t)(h*128+d)*E_ + e];
    #pragma unroll
    for (int i=0;i<32;++i) acc[i] += wv*qb[(size_t)d*64 + i];
  }
  #pragma unroll
  for (int i=0;i<32;++i) Wql[(size_t)(h*64 + lh*32 + i)*E_ + e] = f2b(acc[i]);
}

// ---------------- vupT[h][d][l] = vup[h][l][d], bf16 ----------------
__global__ __launch_bounds__(256)
void k_prep_vupT(const float* __restrict__ vup, ushort* __restrict__ vupT){
  const int h = blockIdx.x, tid = threadIdx.x;
  for (int idx = tid; idx < L_*D_; idx += 256){
    int l = idx >> 7, d = idx & 127;
    vupT[(size_t)h*D_*L_ + d*64 + l] = f2b(vup[(size_t)h*L_*D_ + idx]);
  }
}

// ---------------- BK=64 GEMM: C[M,N] = A[M,K] @ B[N,K]^T --------------------
// 4 waves 2x2; BM=32*MT, BN=32*NT. LDS rows stride 64 ushort (128B) with
// 16B-chunk XOR swizzle (glds SOURCE-permuted; LDS writes stay linear).
// Bijective XCD chunk swizzle. OB16: bf16 out with col-block scale.
template<int MT,int NT,bool OB16>
__global__ __launch_bounds__(256)
void gemm_glds2(const ushort* __restrict__ A, const ushort* __restrict__ B,
                float* __restrict__ Cf, ushort* __restrict__ Cb,
                int M, int N, int K, float scale){
  constexpr int BM = 32*MT, BN = 32*NT;
  constexpr int IA = BM/32, IB = BN/32;     // glds16 per thread per K-step
  __shared__ ushort As[BM*64];
  __shared__ ushort Bs[BN*64];
  const int tid = threadIdx.x, lane = tid&63, wv = tid>>6;
  const int wm = wv & 1, wn = wv >> 1;
  const int l15 = lane&15, quad = lane>>4;
  const int nbx = (int)gridDim.x, nwg = nbx*(int)gridDim.y;  // nwg % 8 == 0
  int bid = (int)blockIdx.y*nbx + (int)blockIdx.x;
  bid = (bid & 7)*(nwg >> 3) + (bid >> 3);
  const int m0 = (bid / nbx)*BM, n0 = (bid % nbx)*BN;
  const float sc = (n0 < 1024) ? scale : 1.0f;     // qkv: ql cols scaled
  floatx4 acc[MT][NT] = {};
  for (int k0=0; k0<K; k0+=64){
    __syncthreads();
    #pragma unroll
    for (int j=0;j<IA;++j){
      int cc = j*256 + tid; int row = cc>>3, kc = ((cc&7)^(row&7))*8;
      glds16(A + (size_t)(m0+row)*K + k0 + kc, &As[cc*8]);
    }
    #pragma unroll
    for (int j=0;j<IB;++j){
      int cc = j*256 + tid; int row = cc>>3, kc = ((cc&7)^(row&7))*8;
      glds16(B + (size_t)(n0+row)*K + k0 + kc, &Bs[cc*8]);
    }
    __syncthreads();
    #pragma unroll
    for (int kk=0;kk<2;++kk){
      bf16x8 af[MT], bfr[NT];
      #pragma unroll
      for (int mi=0;mi<MT;++mi){
        const int r = wm*MT*16 + mi*16 + l15;
        af[mi] = *(const bf16x8*)(&As[r*64 + (((kk*4+quad)^(r&7))<<3)]);
      }
      #pragma unroll
      for (int ni=0;ni<NT;++ni){
        const int r = wn*NT*16 + ni*16 + l15;
        bfr[ni] = *(const bf16x8*)(&Bs[r*64 + (((kk*4+quad)^(r&7))<<3)]);
      }
      #pragma unroll
      for (int mi=0;mi<MT;++mi)
        #pragma unroll
        for (int ni=0;ni<NT;++ni)
          acc[mi][ni] = __builtin_amdgcn_mfma_f32_16x16x32_bf16(af[mi], bfr[ni], acc[mi][ni], 0,0,0);
    }
  }
  #pragma unroll
  for (int mi=0;mi<MT;++mi){
    const int rb = m0 + wm*MT*16 + mi*16 + quad*4;
    #pragma unroll
    for (int ni=0;ni<NT;++ni){
      const int col = n0 + wn*NT*16 + ni*16 + l15;
      #pragma unroll
      for (int r=0;r<4;++r){
        if constexpr (OB16) Cb[(size_t)(rb+r)*N + col] = f2b(acc[mi][ni][r]*sc);
        else                Cf[(size_t)(rb+r)*N + col] = acc[mi][ni][r];
      }
    }
  }
}

// ---------------- rowsums (rsq + rsk, one launch) ----------------
__global__ __launch_bounds__(256)
void k_rowsums(const ushort* __restrict__ qkvb,
               float* __restrict__ rsq, float* __restrict__ rsk){
  int i = blockIdx.x*256 + threadIdx.x;
  const ushort* src; float* dst;
  if (i < T_*H_){
    int t = i>>4, g = i&15;
    src = qkvb + (size_t)t*NQ + g*64; dst = rsq + i;
  } else {
    int t = i - T_*H_;
    if (t >= T_) return;
    src = qkvb + (size_t)t*NQ + 1024; dst = rsk + t;
  }
  const uint4* p = (const uint4*)src;
  float s = 0.f;
  #pragma unroll
  for (int j=0;j<8;++j){
    uint4 u = p[j];
    const unsigned int uu[4] = {u.x,u.y,u.z,u.w};
    #pragma unroll
    for (int q=0;q<4;++q){ s += blo(uu[q]); s += bhi(uu[q]); }
  }
  *dst = s;
}

// ---------------- V_exp^T[h][d][t] via MFMA, register-only ----------------
__global__ __launch_bounds__(256)
void k_vexp_mfma(const ushort* __restrict__ qkvb, const ushort* __restrict__ vupT,
                 ushort* __restrict__ vexpT){
  const int h = blockIdx.y, t0 = blockIdx.x*64;
  const int tid = threadIdx.x, lane = tid&63, w = tid>>6;
  const int l15 = lane&15, quad = lane>>4;
  bf16x8 a[2][2], b[4][2];
  #pragma unroll
  for (int mt=0;mt<2;++mt)
    #pragma unroll
    for (int kk=0;kk<2;++kk)
      a[mt][kk] = *(const bf16x8*)(vupT + (size_t)h*D_*L_ + (w*32+mt*16+l15)*64 + kk*32 + quad*8);
  #pragma unroll
  for (int nt=0;nt<4;++nt)
    #pragma unroll
    for (int kk=0;kk<2;++kk)
      b[nt][kk] = *(const bf16x8*)(qkvb + (size_t)(t0+nt*16+l15)*NQ + 1088 + kk*32 + quad*8);
  floatx4 acc[2][4] = {};
  #pragma unroll
  for (int mt=0;mt<2;++mt)
    #pragma unroll
    for (int nt=0;nt<4;++nt)
      #pragma unroll
      for (int kk=0;kk<2;++kk)
        acc[mt][nt] = __builtin_amdgcn_mfma_f32_16x16x32_bf16(a[mt][kk], b[nt][kk], acc[mt][nt], 0,0,0);
  #pragma unroll
  for (int mt=0;mt<2;++mt)
    #pragma unroll
    for (int nt=0;nt<4;++nt)
      #pragma unroll
      for (int r=0;r<4;++r)
        vexpT[((size_t)h*D_ + w*32+mt*16+quad*4+r)*T_ + t0 + nt*16 + l15] = f2b(acc[mt][nt][r]);
}

// ---------------- flash attention: 1 wave/block, no staging, no barriers ---
// Block = 64 threads. blockIdx.x encodes (qt, c, w): outer=bxr>>2 is the
// old (qt,c) mapping, w=bxr&3 picks the 16-row q sub-tile. K/V fragments
// are loaded straight from global (K 256KB, V/head 512KB: L2-resident).
// Ps = 2KB wave-private LDS scratch for the P bf16 repack (chunk-swizzled).
__global__ __launch_bounds__(64)
void k_attn(const ushort* __restrict__ qkvb,   // [T][1152] bf16
            const float*  __restrict__ rsq,    // [T][16]  (scaled rowsums)
            const float*  __restrict__ rsk,    // [T]
            const ushort* __restrict__ vexpT,  // [16][128][T] bf16
            ushort*       __restrict__ ctx,    // [T][2048] bf16
            ushort*       __restrict__ partO,  // [16][24][4] swizzled 64x128 bf16
            float*        __restrict__ partML, // [16][24][4][64][2]
            int CH){
  __shared__ ushort Ps[16*64];     // 2KB, chunk-swizzled
  const int h  = blockIdx.y;
  const int bxr = (int)gridDim.x - 1 - (int)blockIdx.x;   // heavy tiles first
  const int outer = bxr >> 2, w = bxr & 3;
  int qt, c;
  if (CH == 8){
    if (outer < 8){ qt = outer; c = 0; }
    else if (outer < 24){ int u = outer-8;  qt = 8  + (u>>1); c = u&1; }
    else if (outer < 48){ int u = outer-24; qt = 16 + u/3;    c = u - (u/3)*3; }
    else                { int u = outer-48; qt = 24 + (u>>2); c = u&3; }
  } else { qt = outer; c = 0; }
  const int nct = (qt + CH) / CH;
  const int stBeg = c*CH, stEnd = min(qt, stBeg + CH - 1);
  const int t0 = qt*64;
  const int lane = threadIdx.x;
  const int l15 = lane & 15, quad = lane >> 4;

  const int qrow = t0 + w*16 + l15;
  const bf16x8 q0 = *(const bf16x8*)(qkvb + (size_t)qrow*NQ + h*64 + quad*8);
  const bf16x8 q1 = *(const bf16x8*)(qkvb + (size_t)qrow*NQ + h*64 + 32 + quad*8);
  const float rqv = rsq[(size_t)qrow*H_ + h] * 0.5f;      // already *isl*log2e

  const ushort* vbase = vexpT + (size_t)h*D_*T_;

  float mrun = -INFINITY, lrun = 0.f;
  floatx4 o[8] = {};

  for (int st=stBeg; st<=stEnd; ++st){
    const int s0 = st*64;
    const bool edge = (st >= qt-1);
    // ---- edge rsk loads (broadcast, early) ----
    float4 rk[4];
    if (edge){
      #pragma unroll
      for (int jt=0;jt<4;++jt) rk[jt] = *(const float4*)(rsk + s0 + jt*16 + quad*4);
    }
    // ---- K fragments: global -> regs (coalesced 16-row x 64B) ----
    const ushort* kb = qkvb + (size_t)s0*NQ + 1024;
    bf16x8 k0[4], k1[4];
    #pragma unroll
    for (int jt=0;jt<4;++jt){
      const int srow = jt*16 + l15;
      k0[jt] = *(const bf16x8*)(kb + (size_t)srow*NQ + quad*8);
      k1[jt] = *(const bf16x8*)(kb + (size_t)srow*NQ + 32 + quad*8);
    }
    // ---- V half 0: issued before QK so latency hides under QK+softmax ----
    bf16x8 vf0[8];
    #pragma unroll
    for (int nt=0;nt<8;++nt)
      vf0[nt] = *(const bf16x8*)(vbase + (size_t)(nt*16+l15)*T_ + s0 + quad*8);
    // ---- S^T = K Q^T : lane owns q=l15, s=jt*16+quad*4+r ----
    floatx4 sT[4] = {};
    __builtin_amdgcn_s_setprio(1);
    #pragma unroll
    for (int jt=0;jt<4;++jt){
      sT[jt] = __builtin_amdgcn_mfma_f32_16x16x32_bf16(k0[jt], q0, sT[jt], 0,0,0);
      sT[jt] = __builtin_amdgcn_mfma_f32_16x16x32_bf16(k1[jt], q1, sT[jt], 0,0,0);
    }
    __builtin_amdgcn_s_setprio(0);
    // ---- V half 1: issued here, drains under softmax + PV0 ----
    bf16x8 vf1[8];
    #pragma unroll
    for (int nt=0;nt<8;++nt)
      vf1[nt] = *(const bf16x8*)(vbase + (size_t)(nt*16+l15)*T_ + s0 + 32 + quad*8);
    // ---- mask + rank-1 band (edge tiles only), in place in sT ----
    float mloc = -3.0e38f;
    if (edge){
      #pragma unroll
      for (int jt=0;jt<4;++jt){
        #pragma unroll
        for (int r=0;r<4;++r){
          const int sg = s0 + jt*16 + quad*4 + r;
          const int dd = qrow - sg;
          float x = sT[jt][r];
          x = (dd <= 64) ? x + rqv*((const float*)&rk[jt])[r] : x;
          x = (dd < 0)   ? -3.0e38f : x;
          sT[jt][r] = x; mloc = fmaxf(mloc, x);
        }
      }
    } else {
      #pragma unroll
      for (int jt=0;jt<4;++jt)
        #pragma unroll
        for (int r=0;r<4;++r) mloc = fmaxf(mloc, sT[jt][r]);
    }
    mloc = fmaxf(mloc, __shfl_xor(mloc, 16));
    mloc = fmaxf(mloc, __shfl_xor(mloc, 32));
    // ---- defer-max (T13): keep old max unless it grew by >6 (log2 units) --
    const float mn = (mloc - mrun <= 6.0f) ? mrun : mloc;
    const float al = exp2f(mrun - mn);             // ==1.0 when deferred
    float ss = 0.f;
    #pragma unroll
    for (int jt=0;jt<4;++jt)
      #pragma unroll
      for (int r=0;r<4;++r){
        float p = exp2f(sT[jt][r]-mn); sT[jt][r] = p; ss += p;
      }
    ss += __shfl_xor(ss, 16); ss += __shfl_xor(ss, 32);
    lrun = lrun*al + ss; mrun = mn;
    // ---- P write (wave-private scratch, chunk-swizzled; same-wave order) --
    #pragma unroll
    for (int jt=0;jt<4;++jt){
      unsigned p01, p23;
      asm volatile("v_cvt_pk_bf16_f32 %0, %1, %2" : "=v"(p01) : "v"(sT[jt][0]), "v"(sT[jt][1]));
      asm volatile("v_cvt_pk_bf16_f32 %0, %1, %2" : "=v"(p23) : "v"(sT[jt][2]), "v"(sT[jt][3]));
      const int chunk = 2*jt + (quad>>1);
      uint2 pw2; pw2.x = p01; pw2.y = p23;
      *(uint2*)(&Ps[l15*64 + ((chunk ^ (l15&7))<<3) + (quad&1)*4]) = pw2;
    }
    // ---- rescale O rows (skip when no new max anywhere in wave) ----
    if (__any(al < 1.0f)){
      float alr[4];
      #pragma unroll
      for (int r=0;r<4;++r) alr[r] = __shfl(al, quad*4 + r);
      #pragma unroll
      for (int nt=0;nt<8;++nt){
        o[nt][0]*=alr[0]; o[nt][1]*=alr[1]; o[nt][2]*=alr[2]; o[nt][3]*=alr[3];
      }
    }
    // ---- O += P V (V in registers) ----
    __builtin_amdgcn_s_setprio(1);
    {
      bf16x8 pf0 = *(const bf16x8*)(&Ps[l15*64 + ((quad ^ (l15&7))<<3)]);
      #pragma unroll
      for (int nt=0;nt<8;++nt)
        o[nt] = __builtin_amdgcn_mfma_f32_16x16x32_bf16(pf0, vf0[nt], o[nt], 0,0,0);
      bf16x8 pf1 = *(const bf16x8*)(&Ps[l15*64 + (((4+quad) ^ (l15&7))<<3)]);
      #pragma unroll
      for (int nt=0;nt<8;++nt)
        o[nt] = __builtin_amdgcn_mfma_f32_16x16x32_bf16(pf1, vf1[nt], o[nt], 0,0,0);
    }
    __builtin_amdgcn_s_setprio(0);
  }
  // ---- epilogue ----
  const float linv = 1.f/lrun;
  float lr4[4];
  #pragma unroll
  for (int r=0;r<4;++r) lr4[r] = __shfl(linv, quad*4 + r);
  if (nct == 1){
    #pragma unroll
    for (int r=0;r<4;++r){
      const int row = t0 + w*16 + quad*4 + r;
      #pragma unroll
      for (int nt=0;nt<8;++nt)
        ctx[(size_t)row*E_ + h*D_ + nt*16 + l15] = f2b(o[nt][r]*lr4[r]);
    }
  } else {
    const int slot = (h*24 + (qt-8))*4 + c;
    ushort* po = partO + (size_t)slot*8192;            // swizzled [w][nt][r][lane]
    #pragma unroll
    for (int nt=0;nt<8;++nt)
      #pragma unroll
      for (int r=0;r<4;++r)
        po[((w*8+nt)*4+r)*64 + quad*16 + l15] = f2b(o[nt][r]*lr4[r]);  // 128B/instr
    if (quad == 0){
      float2 ml; ml.x = mrun; ml.y = lrun;
      ((float2*)partML)[(size_t)slot*64 + w*16 + l15] = ml;
    }
  }
}

// ---------------- merge partials -> ctx (qt >= 8) ----------------
__global__ __launch_bounds__(256)
void k_merge(const ushort* __restrict__ partO, const float* __restrict__ partML,
             ushort* __restrict__ ctx){
  const int h = blockIdx.y, qt = 8 + blockIdx.x;
  const int nct = (qt + 8) / 8;
  const int tid = threadIdx.x;
  const int rg = tid >> 2, d0 = (tid & 3)*32;
  const int w = rg >> 4, quad = (rg >> 2) & 3, rr = rg & 3;
  const int n0 = d0 >> 4;
  const int sbase = (h*24 + (qt-8))*4;
  float m[4], l[4], M = -INFINITY;
  for (int c=0;c<4;++c){
    if (c < nct){
      float2 v = ((const float2*)partML)[(size_t)(sbase+c)*64 + rg];
      m[c]=v.x; l[c]=v.y; M = fmaxf(M, v.x);
    }
  }
  float lt = 0.f, wgt[4];
  for (int c=0;c<4;++c){
    if (c < nct){ wgt[c] = exp2f(m[c]-M)*l[c]; lt += wgt[c]; }
  }
  const float inv = 1.f/lt;
  float acc[32];
  #pragma unroll
  for (int i=0;i<32;++i) acc[i]=0.f;
  for (int c=0;c<4;++c){
    if (c >= nct) break;
    const float sc = wgt[c]*inv;
    const ushort* po = partO + (size_t)(sbase+c)*8192;
    #pragma unroll
    for (int nn=0;nn<2;++nn){
      const ushort* p2 = po + ((w*8 + n0+nn)*4 + rr)*64 + quad*16;
      uint4 u  = *(const uint4*)p2;
      uint4 u2 = *(const uint4*)(p2 + 8);
      const unsigned int uu[8] = {u.x,u.y,u.z,u.w,u2.x,u2.y,u2.z,u2.w};
      #pragma unroll
      for (int q=0;q<8;++q){
        acc[nn*16+q*2]   += sc*blo(uu[q]);
        acc[nn*16+q*2+1] += sc*bhi(uu[q]);
      }
    }
  }
  ushort* dst = ctx + (size_t)(qt*64 + rg)*E_ + h*D_ + d0;
  #pragma unroll
  for (int k=0;k<8;++k){
    ushort4 ov; ov.x=f2b(acc[k*4]); ov.y=f2b(acc[k*4+1]);
    ov.z=f2b(acc[k*4+2]); ov.w=f2b(acc[k*4+3]);
    *(ushort4*)(dst + k*4) = ov;
  }
}

// ---------------- launch ----------------
extern "C" void kernel_launch(void* const* d_in, const int* in_sizes, int n_in,
                              void* d_out, int out_size, void* d_ws, size_t ws_size,
                              hipStream_t stream) {
  const float* hs  = (const float*)d_in[0];
  const float* Wq  = (const float*)d_in[1];
  const float* Wk  = (const float*)d_in[2];
  const float* Wv  = (const float*)d_in[3];
  const float* q2l = (const float*)d_in[4];
  const float* vup = (const float*)d_in[5];
  const float* Wo  = (const float*)d_in[6];
  float* out = (float*)d_out;
  char* ws = (char*)d_ws;

  // workspace layout (bytes) — round-6 proven layout
  ushort* hsb   = (ushort*)(ws + 0);           // [2048][2048] bf16
  ushort* Wqkvb = (ushort*)(ws + 8388608);     // [1152][2048] bf16 (ql|k|v)
  ushort* Wob   = (ushort*)(ws + 13107200);    // [2048][2048] bf16
  ushort* qkvb  = (ushort*)(ws + 21495808);    // [2048][1152] bf16
  ushort* vupT  = (ushort*)(ws + 26214400);    // [16][128][64] bf16
  float*  rsqp  = (float*) (ws + 26476544);    // [2048][16]
  float*  rskp  = (float*) (ws + 26607616);    // [2048]
  ushort* vexpT = (ushort*)(ws + 26615808);    // [16][128][2048] bf16
  ushort* ctxb  = (ushort*)(ws + 35004416);    // [2048][2048] bf16
  ushort* partO = (ushort*)(ws + 43393024);    // [16][24][4] x 8192 bf16 (swizzled)
  float*  partML= (float*) (ws + 68558848);    // [16][24][4][64][2]
  const size_t NEED = 69345280;
  const int CH = (ws_size >= NEED) ? 8 : 32;

  // 1) bf16 conversions (hs, Wo, Wk, Wv) in one launch
  k_f2b4<<<8448, 256, 0, stream>>>(hs, hsb, Wo, Wob,
                                   Wk, Wqkvb + (size_t)1024*E_,
                                   Wv, Wqkvb + (size_t)1088*E_);

  // 2) weight prep
  k_prep_wql<<<dim3(16,2,16), 128, 0, stream>>>(Wq, q2l, Wqkvb);
  k_prep_vupT<<<16, 256, 0, stream>>>(vup, vupT);

  // 3) fused q_latent|k|v GEMM -> qkvb [2048][1152] (ql cols pre-scaled)
  //    64x64 tiles, BK=64: 576 blocks (2.25/CU)
  gemm_glds2<2,2,true><<<dim3(18,32), 256, 0, stream>>>(
      hsb, Wqkvb, nullptr, qkvb, T_, NQ, E_, 0.18033688f);

  // 4) rowsums (one launch)
  k_rowsums<<<136, 256, 0, stream>>>(qkvb, rsqp, rskp);

  // 5) V_exp^T via MFMA
  k_vexp_mfma<<<dim3(32,16), 256, 0, stream>>>(qkvb, vupT, vexpT);

  // 6) flash attention (1 wave/block, no staging) -> ctx / partials
  k_attn<<<dim3(CH==8 ? 320 : 128, 16), 64, 0, stream>>>(
      qkvb, rsqp, rskp, vexpT, ctxb, partO, partML, CH);

  // 7) merge partials
  if (CH == 8)
    k_merge<<<dim3(24,16), 256, 0, stream>>>(partO, partML, ctxb);

  // 8) out = ctx @ Wo^T (fp32 to d_out): 64x128 tiles, BK=64, 512 blocks
  gemm_glds2<2,4,false><<<dim3(16,32), 256, 0, stream>>>(
      ctxb, Wob, out, nullptr, T_, E_, E_, 1.0f);
}

// Round 9
// 258.284 us; speedup vs baseline: 1.2542x; 1.2542x over previous
//
#include <hip/hip_runtime.h>

// RA_MLA_Attention — MI355X (gfx950). Round 15.
// B=1, T=2048, E=2048, H=16, D=128, L=64, RA_WINDOW=64, RA_ALPHA=0.5
//
// Round-15 changes (k_attn only; rest byte-identical to r12 = 254.5us champ):
//   * r14 post-mortem: no-staging 1-wave k_attn was 116us (4x L2 traffic,
//     no intra-block reuse) -- staging vindicated, reverted.
//   * k_attn KVBLK 64 -> 128 on the r12 structure (best measured variant):
//     per-tile fixed costs (4 barriers, 2 waits, 2 reduce pairs, rescale,
//     defer branch, loop) halve per column; per-element work unchanged.
//     LDS 64KB (Ks 16K + Vts 32K + Ps 16K), 2 blocks/CU (r13: residency
//     doesn't matter). Chunking 4x128 == old 8x64: merge/partO unchanged.
//   * edge rsk loads at tile top (counted-wait preserved, r13 fix).

#define T_ 2048
#define E_ 2048
#define H_ 16
#define D_ 128
#define L_ 64
#define NQ 1152            // fused qkv GEMM N (1024 ql | 64 k | 64 v)

typedef float  floatx4 __attribute__((ext_vector_type(4)));
typedef __bf16 bf16x8  __attribute__((ext_vector_type(8)));

__device__ __forceinline__ ushort f2b(float x){           // fp32 -> bf16 bits, RNE
  unsigned int u = __float_as_uint(x);
  u = (u + 0x7fffu + ((u >> 16) & 1u)) >> 16;
  return (ushort)u;
}
__device__ __forceinline__ float blo(unsigned int u){ return __uint_as_float(u << 16); }
__device__ __forceinline__ float bhi(unsigned int u){ return __uint_as_float(u & 0xffff0000u); }

__device__ __forceinline__ void glds16(const ushort* g, ushort* l){
#if __has_builtin(__builtin_amdgcn_global_load_lds)
  __builtin_amdgcn_global_load_lds((const __attribute__((address_space(1))) void*)g,
                                   (__attribute__((address_space(3))) void*)l, 16, 0, 0);
#else
  *(uint4*)l = *(const uint4*)g;
#endif
}

// ---------------- fused fp32 -> bf16 convert (4 tensors, 1 launch) ----------
__global__ __launch_bounds__(256)
void k_f2b4(const float* __restrict__ a, ushort* __restrict__ oa,
            const float* __restrict__ b, ushort* __restrict__ ob,
            const float* __restrict__ c, ushort* __restrict__ oc,
            const float* __restrict__ d, ushort* __restrict__ od){
  int bid = blockIdx.x; const float* src; ushort* dst; int base;
  if (bid < 4096){ src=a; dst=oa; base=bid; }
  else if (bid < 8192){ src=b; dst=ob; base=bid-4096; }
  else if (bid < 8320){ src=c; dst=oc; base=bid-8192; }
  else { src=d; dst=od; base=bid-8320; }
  int i = (base*256 + (int)threadIdx.x)*4;
  float4 v = *(const float4*)(src + i);
  ushort4 o; o.x=f2b(v.x); o.y=f2b(v.y); o.z=f2b(v.z); o.w=f2b(v.w);
  *(ushort4*)(dst + i) = o;
}

// ---------------- fold q_to_latent into Wq:  Wql[(h,l),e] (rows of Wqkvb) ----
__global__ __launch_bounds__(128)
void k_prep_wql(const float* __restrict__ Wq, const float* __restrict__ q2l,
                ushort* __restrict__ Wql){
  const int h = blockIdx.z, lh = blockIdx.y;            // l half: lh*32..lh*32+31
  const int e = blockIdx.x*128 + threadIdx.x;
  const float* qb = q2l + (size_t)h*D_*L_ + lh*32;
  float acc[32];
  #pragma unroll
  for (int i=0;i<32;++i) acc[i]=0.f;
  for (int d=0; d<128; ++d){
    float wv = Wq[(size_t)(h*128+d)*E_ + e];
    #pragma unroll
    for (int i=0;i<32;++i) acc[i] += wv*qb[(size_t)d*64 + i];
  }
  #pragma unroll
  for (int i=0;i<32;++i) Wql[(size_t)(h*64 + lh*32 + i)*E_ + e] = f2b(acc[i]);
}

// ---------------- vupT[h][d][l] = vup[h][l][d], bf16 ----------------
__global__ __launch_bounds__(256)
void k_prep_vupT(const float* __restrict__ vup, ushort* __restrict__ vupT){
  const int h = blockIdx.x, tid = threadIdx.x;
  for (int idx = tid; idx < L_*D_; idx += 256){
    int l = idx >> 7, d = idx & 127;
    vupT[(size_t)h*D_*L_ + d*64 + l] = f2b(vup[(size_t)h*L_*D_ + idx]);
  }
}

// ---------------- BK=64 GEMM: C[M,N] = A[M,K] @ B[N,K]^T --------------------
// 4 waves 2x2; BM=32*MT, BN=32*NT. LDS rows stride 64 ushort (128B) with
// 16B-chunk XOR swizzle (glds SOURCE-permuted; LDS writes stay linear).
// Bijective XCD chunk swizzle. OB16: bf16 out with col-block scale.
template<int MT,int NT,bool OB16>
__global__ __launch_bounds__(256)
void gemm_glds2(const ushort* __restrict__ A, const ushort* __restrict__ B,
                float* __restrict__ Cf, ushort* __restrict__ Cb,
                int M, int N, int K, float scale){
  constexpr int BM = 32*MT, BN = 32*NT;
  constexpr int IA = BM/32, IB = BN/32;     // glds16 per thread per K-step
  __shared__ ushort As[BM*64];
  __shared__ ushort Bs[BN*64];
  const int tid = threadIdx.x, lane = tid&63, wv = tid>>6;
  const int wm = wv & 1, wn = wv >> 1;
  const int l15 = lane&15, quad = lane>>4;
  const int nbx = (int)gridDim.x, nwg = nbx*(int)gridDim.y;  // nwg % 8 == 0
  int bid = (int)blockIdx.y*nbx + (int)blockIdx.x;
  bid = (bid & 7)*(nwg >> 3) + (bid >> 3);
  const int m0 = (bid / nbx)*BM, n0 = (bid % nbx)*BN;
  const float sc = (n0 < 1024) ? scale : 1.0f;     // qkv: ql cols scaled
  floatx4 acc[MT][NT] = {};
  for (int k0=0; k0<K; k0+=64){
    __syncthreads();
    #pragma unroll
    for (int j=0;j<IA;++j){
      int cc = j*256 + tid; int row = cc>>3, kc = ((cc&7)^(row&7))*8;
      glds16(A + (size_t)(m0+row)*K + k0 + kc, &As[cc*8]);
    }
    #pragma unroll
    for (int j=0;j<IB;++j){
      int cc = j*256 + tid; int row = cc>>3, kc = ((cc&7)^(row&7))*8;
      glds16(B + (size_t)(n0+row)*K + k0 + kc, &Bs[cc*8]);
    }
    __syncthreads();
    #pragma unroll
    for (int kk=0;kk<2;++kk){
      bf16x8 af[MT], bfr[NT];
      #pragma unroll
      for (int mi=0;mi<MT;++mi){
        const int r = wm*MT*16 + mi*16 + l15;
        af[mi] = *(const bf16x8*)(&As[r*64 + (((kk*4+quad)^(r&7))<<3)]);
      }
      #pragma unroll
      for (int ni=0;ni<NT;++ni){
        const int r = wn*NT*16 + ni*16 + l15;
        bfr[ni] = *(const bf16x8*)(&Bs[r*64 + (((kk*4+quad)^(r&7))<<3)]);
      }
      #pragma unroll
      for (int mi=0;mi<MT;++mi)
        #pragma unroll
        for (int ni=0;ni<NT;++ni)
          acc[mi][ni] = __builtin_amdgcn_mfma_f32_16x16x32_bf16(af[mi], bfr[ni], acc[mi][ni], 0,0,0);
    }
  }
  #pragma unroll
  for (int mi=0;mi<MT;++mi){
    const int rb = m0 + wm*MT*16 + mi*16 + quad*4;
    #pragma unroll
    for (int ni=0;ni<NT;++ni){
      const int col = n0 + wn*NT*16 + ni*16 + l15;
      #pragma unroll
      for (int r=0;r<4;++r){
        if constexpr (OB16) Cb[(size_t)(rb+r)*N + col] = f2b(acc[mi][ni][r]*sc);
        else                Cf[(size_t)(rb+r)*N + col] = acc[mi][ni][r];
      }
    }
  }
}

// ---------------- rowsums (rsq + rsk, one launch) ----------------
__global__ __launch_bounds__(256)
void k_rowsums(const ushort* __restrict__ qkvb,
               float* __restrict__ rsq, float* __restrict__ rsk){
  int i = blockIdx.x*256 + threadIdx.x;
  const ushort* src; float* dst;
  if (i < T_*H_){
    int t = i>>4, g = i&15;
    src = qkvb + (size_t)t*NQ + g*64; dst = rsq + i;
  } else {
    int t = i - T_*H_;
    if (t >= T_) return;
    src = qkvb + (size_t)t*NQ + 1024; dst = rsk + t;
  }
  const uint4* p = (const uint4*)src;
  float s = 0.f;
  #pragma unroll
  for (int j=0;j<8;++j){
    uint4 u = p[j];
    const unsigned int uu[4] = {u.x,u.y,u.z,u.w};
    #pragma unroll
    for (int q=0;q<4;++q){ s += blo(uu[q]); s += bhi(uu[q]); }
  }
  *dst = s;
}

// ---------------- V_exp^T[h][d][t] via MFMA, register-only ----------------
__global__ __launch_bounds__(256)
void k_vexp_mfma(const ushort* __restrict__ qkvb, const ushort* __restrict__ vupT,
                 ushort* __restrict__ vexpT){
  const int h = blockIdx.y, t0 = blockIdx.x*64;
  const int tid = threadIdx.x, lane = tid&63, w = tid>>6;
  const int l15 = lane&15, quad = lane>>4;
  bf16x8 a[2][2], b[4][2];
  #pragma unroll
  for (int mt=0;mt<2;++mt)
    #pragma unroll
    for (int kk=0;kk<2;++kk)
      a[mt][kk] = *(const bf16x8*)(vupT + (size_t)h*D_*L_ + (w*32+mt*16+l15)*64 + kk*32 + quad*8);
  #pragma unroll
  for (int nt=0;nt<4;++nt)
    #pragma unroll
    for (int kk=0;kk<2;++kk)
      b[nt][kk] = *(const bf16x8*)(qkvb + (size_t)(t0+nt*16+l15)*NQ + 1088 + kk*32 + quad*8);
  floatx4 acc[2][4] = {};
  #pragma unroll
  for (int mt=0;mt<2;++mt)
    #pragma unroll
    for (int nt=0;nt<4;++nt)
      #pragma unroll
      for (int kk=0;kk<2;++kk)
        acc[mt][nt] = __builtin_amdgcn_mfma_f32_16x16x32_bf16(a[mt][kk], b[nt][kk], acc[mt][nt], 0,0,0);
  #pragma unroll
  for (int mt=0;mt<2;++mt)
    #pragma unroll
    for (int nt=0;nt<4;++nt)
      #pragma unroll
      for (int r=0;r<4;++r)
        vexpT[((size_t)h*D_ + w*32+mt*16+quad*4+r)*T_ + t0 + nt*16 + l15] = f2b(acc[mt][nt][r]);
}

// ---------------- flash attention, split-S, KVBLK=128 ---------------------
// Block = (head, 64-row Q-tile qt, chunk c of 4 x 128-col tiles). 4 waves.
// K/V LDS single-buffered, r12 counted-vmcnt disjoint-phase pipeline:
//   vmcnt(8)->bar->QK->bar-> stageK(t+1) -> softmax ->
//   vmcnt(4)->bar->PV->bar-> stageV(t+1)
// K: [128s][64l] 16KB; V: [128d][128s] 32KB; Ps: 4x[16q][128s] 16KB.
// All LDS rows 16B-chunk XOR-swizzled (source-permuted glds, linear writes).
__global__ __launch_bounds__(256, 2)
void k_attn(const ushort* __restrict__ qkvb,   // [T][1152] bf16
            const float*  __restrict__ rsq,    // [T][16]  (scaled rowsums)
            const float*  __restrict__ rsk,    // [T]
            const ushort* __restrict__ vexpT,  // [16][128][T] bf16
            ushort*       __restrict__ ctx,    // [T][2048] bf16
            ushort*       __restrict__ partO,  // [16][24][4] swizzled 64x128 bf16
            float*        __restrict__ partML, // [16][24][4][64][2]
            int CH){
  __shared__ ushort Ks[128*64];     // 16KB
  __shared__ ushort Vts[128*128];   // 32KB
  __shared__ ushort Ps[4*16*128];   // 16KB
  const int h  = blockIdx.y;
  const int bxr = (int)gridDim.x - 1 - (int)blockIdx.x;   // heavy tiles first
  int qt, c;
  if (CH == 8){
    if (bxr < 8){ qt = bxr; c = 0; }
    else if (bxr < 24){ int u = bxr-8;  qt = 8  + (u>>1); c = u&1; }
    else if (bxr < 48){ int u = bxr-24; qt = 16 + u/3;    c = u - (u/3)*3; }
    else               { int u = bxr-48; qt = 24 + (u>>2); c = u&3; }
  } else { qt = bxr; c = 0; }
  const int nct = (qt + CH) / CH;
  const int stBeg = c*4;                                   // 128-col units
  const int stEnd = (CH==8) ? min(qt>>1, c*4+3) : (qt>>1);
  const int t0 = qt*64;
  const int tid = threadIdx.x, lane = tid & 63, w = tid >> 6;
  const int l15 = lane & 15, quad = lane >> 4;

  auto stageK = [&](int s0k){                              // 4 glds/thread
    #pragma unroll
    for (int j=0;j<4;++j){ int cc = tid + j*256;
      int row = cc>>3, kc = ((cc&7) ^ (row&7))*8;
      glds16(qkvb + (size_t)(s0k + row)*NQ + 1024 + kc, &Ks[cc*8]); }
  };
  auto stageV = [&](int s0v){                              // 8 glds/thread
    #pragma unroll
    for (int j=0;j<8;++j){ int cc = tid + j*256;
      int row = cc>>4, sc2 = ((cc&15) ^ (row&7))*8;
      glds16(vexpT + ((size_t)h*128 + row)*T_ + s0v + sc2, &Vts[cc*8]); }
  };

  const int qrow = t0 + w*16 + l15;
  const bf16x8 q0 = *(const bf16x8*)(qkvb + (size_t)qrow*NQ + h*64 + quad*8);
  const bf16x8 q1 = *(const bf16x8*)(qkvb + (size_t)qrow*NQ + h*64 + 32 + quad*8);
  const float rqv = rsq[(size_t)qrow*H_ + h] * 0.5f;      // already *isl*log2e

  float mrun = -INFINITY, lrun = 0.f;
  floatx4 o[8] = {};

  stageK(stBeg*128); stageV(stBeg*128);              // prologue: 4 + 8 loads

  for (int st=stBeg; st<=stEnd; ++st){
    const int s0 = st*128;
    const bool more = (st < stEnd);
    const bool edge = (2*st + 3 > qt);
    // ---- edge rsk loads first (keeps waits counted) ----
    float4 rk[8];
    if (edge){
      #pragma unroll
      for (int jt=0;jt<8;++jt) rk[jt] = *(const float4*)(rsk + s0 + jt*16 + quad*4);
    }
    // ---- K(st) landed (V(st)'s 8 loads still in flight) ----
    if (more || edge) asm volatile("s_waitcnt vmcnt(8)" ::: "memory");
    else              asm volatile("s_waitcnt vmcnt(8)" ::: "memory");
    __builtin_amdgcn_s_barrier();
    __builtin_amdgcn_sched_barrier(0);
    // ---- S^T = K Q^T : lane owns q=l15, s=jt*16+quad*4+r, jt 0..7 ----
    floatx4 sT[8] = {};
    __builtin_amdgcn_s_setprio(1);
    #pragma unroll
    for (int jt=0;jt<8;++jt){
      const int srow = jt*16 + l15, sx = srow & 7;
      bf16x8 k0f = *(const bf16x8*)(&Ks[srow*64 + ((quad^sx))*8]);
      sT[jt] = __builtin_amdgcn_mfma_f32_16x16x32_bf16(k0f, q0, sT[jt], 0,0,0);
      bf16x8 k1f = *(const bf16x8*)(&Ks[srow*64 + (((4+quad)^sx))*8]);
      sT[jt] = __builtin_amdgcn_mfma_f32_16x16x32_bf16(k1f, q1, sT[jt], 0,0,0);
    }
    __builtin_amdgcn_s_setprio(0);
    __builtin_amdgcn_sched_barrier(0);
    __builtin_amdgcn_s_barrier();                  // all K reads done
    if (more) stageK(s0 + 128);                    // K(t+1) under softmax+PV
    // ---- mask + rank-1 band (edge tiles only), in place in sT ----
    float mloc = -3.0e38f;
    if (edge){
      #pragma unroll
      for (int jt=0;jt<8;++jt){
        #pragma unroll
        for (int r=0;r<4;++r){
          const int sg = s0 + jt*16 + quad*4 + r;
          const int dd = qrow - sg;
          float x = sT[jt][r];
          x = (dd <= 64) ? x + rqv*((const float*)&rk[jt])[r] : x;
          x = (dd < 0)   ? -3.0e38f : x;
          sT[jt][r] = x; mloc = fmaxf(mloc, x);
        }
      }
    } else {
      #pragma unroll
      for (int jt=0;jt<8;++jt)
        #pragma unroll
        for (int r=0;r<4;++r) mloc = fmaxf(mloc, sT[jt][r]);
    }
    mloc = fmaxf(mloc, __shfl_xor(mloc, 16));
    mloc = fmaxf(mloc, __shfl_xor(mloc, 32));
    // ---- defer-max (T13): keep old max unless it grew by >6 (log2 units) --
    const float mn = (mloc - mrun <= 6.0f) ? mrun : mloc;
    const float al = exp2f(mrun - mn);             // ==1.0 when deferred
    float ss = 0.f;
    #pragma unroll
    for (int jt=0;jt<8;++jt)
      #pragma unroll
      for (int r=0;r<4;++r){
        float p = exp2f(sT[jt][r]-mn); sT[jt][r] = p; ss += p;
      }
    ss += __shfl_xor(ss, 16); ss += __shfl_xor(ss, 32);
    lrun = lrun*al + ss; mrun = mn;
    // ---- P write (wave-private rows, chunk-swizzled; same-wave order) ----
    #pragma unroll
    for (int jt=0;jt<8;++jt){
      unsigned p01, p23;
      asm volatile("v_cvt_pk_bf16_f32 %0, %1, %2" : "=v"(p01) : "v"(sT[jt][0]), "v"(sT[jt][1]));
      asm volatile("v_cvt_pk_bf16_f32 %0, %1, %2" : "=v"(p23) : "v"(sT[jt][2]), "v"(sT[jt][3]));
      const int chunk = 2*jt + (quad>>1);
      uint2 pw2; pw2.x = p01; pw2.y = p23;
      *(uint2*)(&Ps[(w*16 + l15)*128 + ((chunk ^ (l15&7))<<3) + (quad&1)*4]) = pw2;
    }
    // ---- rescale O rows (skip when no new max anywhere in wave) ----
    if (__any(al < 1.0f)){
      float alr[4];
      #pragma unroll
      for (int r=0;r<4;++r) alr[r] = __shfl(al, quad*4 + r);
      #pragma unroll
      for (int nt=0;nt<8;++nt){
        o[nt][0]*=alr[0]; o[nt][1]*=alr[1]; o[nt][2]*=alr[2]; o[nt][3]*=alr[3];
      }
    }
    // ---- V(st) landed (K(t+1)'s 4 loads still in flight) ----
    __builtin_amdgcn_sched_barrier(0);
    if (more) asm volatile("s_waitcnt vmcnt(4)" ::: "memory");
    else      asm volatile("s_waitcnt vmcnt(0)" ::: "memory");
    __builtin_amdgcn_s_barrier();
    __builtin_amdgcn_sched_barrier(0);
    // ---- O += P V : kks 0..3 covers s=kks*32..+31 ----
    __builtin_amdgcn_s_setprio(1);
    #pragma unroll
    for (int kks=0;kks<4;++kks){
      const int ch = kks*4 + quad;
      bf16x8 pf = *(const bf16x8*)(&Ps[(w*16 + l15)*128 + ((ch ^ (l15&7))<<3)]);
      #pragma unroll
      for (int nt=0;nt<8;++nt){
        const int vrow = nt*16 + l15, vx = vrow & 7;
        bf16x8 vf = *(const bf16x8*)(&Vts[vrow*128 + ((ch^vx)<<3)]);
        o[nt] = __builtin_amdgcn_mfma_f32_16x16x32_bf16(pf, vf, o[nt], 0,0,0);
      }
    }
    __builtin_amdgcn_s_setprio(0);
    __builtin_amdgcn_sched_barrier(0);
    if (more){
      __builtin_amdgcn_s_barrier();                // all V reads done
      stageV(s0 + 128);                            // V(t+1) under next QK+softmax
    }
  }
  // ---- epilogue ----
  const float linv = 1.f/lrun;
  float lr4[4];
  #pragma unroll
  for (int r=0;r<4;++r) lr4[r] = __shfl(linv, quad*4 + r);
  if (nct == 1){
    #pragma unroll
    for (int r=0;r<4;++r){
      const int row = t0 + w*16 + quad*4 + r;
      #pragma unroll
      for (int nt=0;nt<8;++nt)
        ctx[(size_t)row*E_ + h*D_ + nt*16 + l15] = f2b(o[nt][r]*lr4[r]);
    }
  } else {
    const int slot = (h*24 + (qt-8))*4 + c;
    ushort* po = partO + (size_t)slot*8192;            // swizzled [w][nt][r][lane]
    #pragma unroll
    for (int nt=0;nt<8;++nt)
      #pragma unroll
      for (int r=0;r<4;++r)
        po[((w*8+nt)*4+r)*64 + quad*16 + l15] = f2b(o[nt][r]*lr4[r]);  // 128B/instr
    if (quad == 0){
      float2 ml; ml.x = mrun; ml.y = lrun;
      ((float2*)partML)[(size_t)slot*64 + w*16 + l15] = ml;
    }
  }
}

// ---------------- merge partials -> ctx (qt >= 8) ----------------
__global__ __launch_bounds__(256)
void k_merge(const ushort* __restrict__ partO, const float* __restrict__ partML,
             ushort* __restrict__ ctx){
  const int h = blockIdx.y, qt = 8 + blockIdx.x;
  const int nct = (qt + 8) / 8;
  const int tid = threadIdx.x;
  const int rg = tid >> 2, d0 = (tid & 3)*32;
  const int w = rg >> 4, quad = (rg >> 2) & 3, rr = rg & 3;
  const int n0 = d0 >> 4;
  const int sbase = (h*24 + (qt-8))*4;
  float m[4], l[4], M = -INFINITY;
  for (int c=0;c<4;++c){
    if (c < nct){
      float2 v = ((const float2*)partML)[(size_t)(sbase+c)*64 + rg];
      m[c]=v.x; l[c]=v.y; M = fmaxf(M, v.x);
    }
  }
  float lt = 0.f, wgt[4];
  for (int c=0;c<4;++c){
    if (c < nct){ wgt[c] = exp2f(m[c]-M)*l[c]; lt += wgt[c]; }
  }
  const float inv = 1.f/lt;
  float acc[32];
  #pragma unroll
  for (int i=0;i<32;++i) acc[i]=0.f;
  for (int c=0;c<4;++c){
    if (c >= nct) break;
    const float sc = wgt[c]*inv;
    const ushort* po = partO + (size_t)(sbase+c)*8192;
    #pragma unroll
    for (int nn=0;nn<2;++nn){
      const ushort* p2 = po + ((w*8 + n0+nn)*4 + rr)*64 + quad*16;
      uint4 u  = *(const uint4*)p2;
      uint4 u2 = *(const uint4*)(p2 + 8);
      const unsigned int uu[8] = {u.x,u.y,u.z,u.w,u2.x,u2.y,u2.z,u2.w};
      #pragma unroll
      for (int q=0;q<8;++q){
        acc[nn*16+q*2]   += sc*blo(uu[q]);
        acc[nn*16+q*2+1] += sc*bhi(uu[q]);
      }
    }
  }
  ushort* dst = ctx + (size_t)(qt*64 + rg)*E_ + h*D_ + d0;
  #pragma unroll
  for (int k=0;k<8;++k){
    ushort4 ov; ov.x=f2b(acc[k*4]); ov.y=f2b(acc[k*4+1]);
    ov.z=f2b(acc[k*4+2]); ov.w=f2b(acc[k*4+3]);
    *(ushort4*)(dst + k*4) = ov;
  }
}

// ---------------- launch ----------------
extern "C" void kernel_launch(void* const* d_in, const int* in_sizes, int n_in,
                              void* d_out, int out_size, void* d_ws, size_t ws_size,
                              hipStream_t stream) {
  const float* hs  = (const float*)d_in[0];
  const float* Wq  = (const float*)d_in[1];
  const float* Wk  = (const float*)d_in[2];
  const float* Wv  = (const float*)d_in[3];
  const float* q2l = (const float*)d_in[4];
  const float* vup = (const float*)d_in[5];
  const float* Wo  = (const float*)d_in[6];
  float* out = (float*)d_out;
  char* ws = (char*)d_ws;

  // workspace layout (bytes) — round-6 proven layout
  ushort* hsb   = (ushort*)(ws + 0);           // [2048][2048] bf16
  ushort* Wqkvb = (ushort*)(ws + 8388608);     // [1152][2048] bf16 (ql|k|v)
  ushort* Wob   = (ushort*)(ws + 13107200);    // [2048][2048] bf16
  ushort* qkvb  = (ushort*)(ws + 21495808);    // [2048][1152] bf16
  ushort* vupT  = (ushort*)(ws + 26214400);    // [16][128][64] bf16
  float*  rsqp  = (float*) (ws + 26476544);    // [2048][16]
  float*  rskp  = (float*) (ws + 26607616);    // [2048]
  ushort* vexpT = (ushort*)(ws + 26615808);    // [16][128][2048] bf16
  ushort* ctxb  = (ushort*)(ws + 35004416);    // [2048][2048] bf16
  ushort* partO = (ushort*)(ws + 43393024);    // [16][24][4] x 8192 bf16 (swizzled)
  float*  partML= (float*) (ws + 68558848);    // [16][24][4][64][2]
  const size_t NEED = 69345280;
  const int CH = (ws_size >= NEED) ? 8 : 32;

  // 1) bf16 conversions (hs, Wo, Wk, Wv) in one launch
  k_f2b4<<<8448, 256, 0, stream>>>(hs, hsb, Wo, Wob,
                                   Wk, Wqkvb + (size_t)1024*E_,
                                   Wv, Wqkvb + (size_t)1088*E_);

  // 2) weight prep
  k_prep_wql<<<dim3(16,2,16), 128, 0, stream>>>(Wq, q2l, Wqkvb);
  k_prep_vupT<<<16, 256, 0, stream>>>(vup, vupT);

  // 3) fused q_latent|k|v GEMM -> qkvb [2048][1152] (ql cols pre-scaled)
  //    64x64 tiles, BK=64: 576 blocks (2.25/CU)
  gemm_glds2<2,2,true><<<dim3(18,32), 256, 0, stream>>>(
      hsb, Wqkvb, nullptr, qkvb, T_, NQ, E_, 0.18033688f);

  // 4) rowsums (one launch)
  k_rowsums<<<136, 256, 0, stream>>>(qkvb, rsqp, rskp);

  // 5) V_exp^T via MFMA
  k_vexp_mfma<<<dim3(32,16), 256, 0, stream>>>(qkvb, vupT, vexpT);

  // 6) flash attention (split-S, KVBLK=128) -> ctx / partials
  k_attn<<<dim3(CH==8 ? 80 : 32, 16), 256, 0, stream>>>(
      qkvb, rsqp, rskp, vexpT, ctxb, partO, partML, CH);

  // 7) merge partials
  if (CH == 8)
    k_merge<<<dim3(24,16), 256, 0, stream>>>(partO, partML, ctxb);

  // 8) out = ctx @ Wo^T (fp32 to d_out): 64x128 tiles, BK=64, 512 blocks
  gemm_glds2<2,4,false><<<dim3(16,32), 256, 0, stream>>>(
      ctxb, Wob, out, nullptr, T_, E_, E_, 1.0f);
}

// Round 10
// 242.677 us; speedup vs baseline: 1.3349x; 1.0643x over previous
//
#include <hip/hip_runtime.h>

// RA_MLA_Attention — MI355X (gfx950). Round 16.
// B=1, T=2048, E=2048, H=16, D=128, L=64, RA_WINDOW=64, RA_ALPHA=0.5
//
// Round-16 changes:
//   * k_attn reverted VERBATIM to r12 (43.7us champion; r15's KVBLK=128
//     regressed via 3M bank conflicts from a botched 256B-row swizzle).
//   * Dispatch count 9 -> 6 (launch-gap theory: big3+smalls sum to ~160us
//     of 254.5 -> ~90us lives between dispatches):
//       - k_prep fuses f2b4 + prep_wql + prep_vupT (independent work).
//       - rowsums folded into qkv GEMM epilogue (RS flag): BN=64 tile
//         n0=h*64 holds all of head h's cols -> shfl+LDS reduce from
//         fp32 acc writes rsq/rsk. k_rowsums deleted.

#define T_ 2048
#define E_ 2048
#define H_ 16
#define D_ 128
#define L_ 64
#define NQ 1152            // fused qkv GEMM N (1024 ql | 64 k | 64 v)

typedef float  floatx4 __attribute__((ext_vector_type(4)));
typedef __bf16 bf16x8  __attribute__((ext_vector_type(8)));

__device__ __forceinline__ ushort f2b(float x){           // fp32 -> bf16 bits, RNE
  unsigned int u = __float_as_uint(x);
  u = (u + 0x7fffu + ((u >> 16) & 1u)) >> 16;
  return (ushort)u;
}
__device__ __forceinline__ float blo(unsigned int u){ return __uint_as_float(u << 16); }
__device__ __forceinline__ float bhi(unsigned int u){ return __uint_as_float(u & 0xffff0000u); }

__device__ __forceinline__ void glds16(const ushort* g, ushort* l){
#if __has_builtin(__builtin_amdgcn_global_load_lds)
  __builtin_amdgcn_global_load_lds((const __attribute__((address_space(1))) void*)g,
                                   (__attribute__((address_space(3))) void*)l, 16, 0, 0);
#else
  *(uint4*)l = *(const uint4*)g;
#endif
}

// ---------------- fused prep: f2b4 + wql-fold + vupT (one launch) ----------
__global__ __launch_bounds__(256)
void k_prep(const float* __restrict__ hs, ushort* __restrict__ hsb,
            const float* __restrict__ Wo, ushort* __restrict__ Wob,
            const float* __restrict__ Wk, ushort* __restrict__ Wkb,
            const float* __restrict__ Wv, ushort* __restrict__ Wvb,
            const float* __restrict__ Wq, const float* __restrict__ q2l,
            ushort* __restrict__ Wql,
            const float* __restrict__ vup, ushort* __restrict__ vupT){
  const int bid = blockIdx.x;
  if (bid < 8448){
    // ---- fp32 -> bf16 conversions ----
    const float* src; ushort* dst; int base;
    if (bid < 4096){ src=hs; dst=hsb; base=bid; }
    else if (bid < 8192){ src=Wo; dst=Wob; base=bid-4096; }
    else if (bid < 8320){ src=Wk; dst=Wkb; base=bid-8192; }
    else { src=Wv; dst=Wvb; base=bid-8320; }
    int i = (base*256 + (int)threadIdx.x)*4;
    float4 v = *(const float4*)(src + i);
    ushort4 o; o.x=f2b(v.x); o.y=f2b(v.y); o.z=f2b(v.z); o.w=f2b(v.w);
    *(ushort4*)(dst + i) = o;
  } else if (bid < 8960){
    // ---- fold q_to_latent into Wq: Wql[(h,l),e] ----
    if (threadIdx.x >= 128) return;
    const int b2 = bid - 8448;
    const int h = b2 >> 5, lh = (b2 >> 4) & 1, ex = b2 & 15;
    const int e = ex*128 + (int)threadIdx.x;
    const float* qb = q2l + (size_t)h*D_*L_ + lh*32;
    float acc[32];
    #pragma unroll
    for (int i=0;i<32;++i) acc[i]=0.f;
    for (int d=0; d<128; ++d){
      float wv = Wq[(size_t)(h*128+d)*E_ + e];
      #pragma unroll
      for (int i=0;i<32;++i) acc[i] += wv*qb[(size_t)d*64 + i];
    }
    #pragma unroll
    for (int i=0;i<32;++i) Wql[(size_t)(h*64 + lh*32 + i)*E_ + e] = f2b(acc[i]);
  } else {
    // ---- vupT[h][d][l] = vup[h][l][d] ----
    const int h = bid - 8960, tid = threadIdx.x;
    for (int idx = tid; idx < L_*D_; idx += 256){
      int l = idx >> 7, d = idx & 127;
      vupT[(size_t)h*D_*L_ + d*64 + l] = f2b(vup[(size_t)h*L_*D_ + idx]);
    }
  }
}

// ---------------- BK=64 GEMM: C[M,N] = A[M,K] @ B[N,K]^T --------------------
// 4 waves 2x2; BM=32*MT, BN=32*NT. LDS rows stride 64 ushort (128B) with
// 16B-chunk XOR swizzle (glds SOURCE-permuted; LDS writes stay linear).
// Bijective XCD chunk swizzle. OB16: bf16 out with col-block scale.
// RS: rowsum epilogue (qkv only, BN=64): rsq for ql tiles, rsk for k tile.
template<int MT,int NT,bool OB16,bool RS>
__global__ __launch_bounds__(256)
void gemm_glds2(const ushort* __restrict__ A, const ushort* __restrict__ B,
                float* __restrict__ Cf, ushort* __restrict__ Cb,
                float* __restrict__ rsq, float* __restrict__ rsk,
                int M, int N, int K, float scale){
  constexpr int BM = 32*MT, BN = 32*NT;
  constexpr int IA = BM/32, IB = BN/32;     // glds16 per thread per K-step
  __shared__ ushort As[BM*64];
  __shared__ ushort Bs[BN*64];
  const int tid = threadIdx.x, lane = tid&63, wv = tid>>6;
  const int wm = wv & 1, wn = wv >> 1;
  const int l15 = lane&15, quad = lane>>4;
  const int nbx = (int)gridDim.x, nwg = nbx*(int)gridDim.y;  // nwg % 8 == 0
  int bid = (int)blockIdx.y*nbx + (int)blockIdx.x;
  bid = (bid & 7)*(nwg >> 3) + (bid >> 3);
  const int m0 = (bid / nbx)*BM, n0 = (bid % nbx)*BN;
  const float sc = (n0 < 1024) ? scale : 1.0f;     // qkv: ql cols scaled
  floatx4 acc[MT][NT] = {};
  for (int k0=0; k0<K; k0+=64){
    __syncthreads();
    #pragma unroll
    for (int j=0;j<IA;++j){
      int cc = j*256 + tid; int row = cc>>3, kc = ((cc&7)^(row&7))*8;
      glds16(A + (size_t)(m0+row)*K + k0 + kc, &As[cc*8]);
    }
    #pragma unroll
    for (int j=0;j<IB;++j){
      int cc = j*256 + tid; int row = cc>>3, kc = ((cc&7)^(row&7))*8;
      glds16(B + (size_t)(n0+row)*K + k0 + kc, &Bs[cc*8]);
    }
    __syncthreads();
    #pragma unroll
    for (int kk=0;kk<2;++kk){
      bf16x8 af[MT], bfr[NT];
      #pragma unroll
      for (int mi=0;mi<MT;++mi){
        const int r = wm*MT*16 + mi*16 + l15;
        af[mi] = *(const bf16x8*)(&As[r*64 + (((kk*4+quad)^(r&7))<<3)]);
      }
      #pragma unroll
      for (int ni=0;ni<NT;++ni){
        const int r = wn*NT*16 + ni*16 + l15;
        bfr[ni] = *(const bf16x8*)(&Bs[r*64 + (((kk*4+quad)^(r&7))<<3)]);
      }
      #pragma unroll
      for (int mi=0;mi<MT;++mi)
        #pragma unroll
        for (int ni=0;ni<NT;++ni)
          acc[mi][ni] = __builtin_amdgcn_mfma_f32_16x16x32_bf16(af[mi], bfr[ni], acc[mi][ni], 0,0,0);
    }
  }
  #pragma unroll
  for (int mi=0;mi<MT;++mi){
    const int rb = m0 + wm*MT*16 + mi*16 + quad*4;
    #pragma unroll
    for (int ni=0;ni<NT;++ni){
      const int col = n0 + wn*NT*16 + ni*16 + l15;
      #pragma unroll
      for (int r=0;r<4;++r){
        if constexpr (OB16) Cb[(size_t)(rb+r)*N + col] = f2b(acc[mi][ni][r]*sc);
        else                Cf[(size_t)(rb+r)*N + col] = acc[mi][ni][r];
      }
    }
  }
  if constexpr (RS){
    // rowsums from fp32 acc: ql tiles (n0<1024) -> rsq[t][h]; k tile
    // (n0==1024) -> rsk[t]; v tile (n0==1088) skipped.
    if (n0 != 1088){
      float rp[MT][4];
      #pragma unroll
      for (int mi=0;mi<MT;++mi)
        #pragma unroll
        for (int r=0;r<4;++r){
          float v = 0.f;
          #pragma unroll
          for (int ni=0;ni<NT;++ni) v += acc[mi][ni][r];
          #pragma unroll
          for (int off=1;off<16;off<<=1) v += __shfl_xor(v, off);
          rp[mi][r] = v;
        }
      float* Asf = (float*)As;
      __syncthreads();                    // all waves done with As reads
      if (l15 == 0){
        #pragma unroll
        for (int mi=0;mi<MT;++mi)
          #pragma unroll
          for (int r=0;r<4;++r)
            Asf[wn*BM + wm*MT*16 + mi*16 + quad*4 + r] = rp[mi][r];
      }
      __syncthreads();
      if (tid < BM){
        float total = Asf[tid] + Asf[BM + tid];
        if (n0 < 1024) rsq[(size_t)(m0+tid)*H_ + (n0>>6)] = total*scale;
        else           rsk[m0+tid] = total;
      }
    }
  }
}

// ---------------- V_exp^T[h][d][t] via MFMA, register-only ----------------
__global__ __launch_bounds__(256)
void k_vexp_mfma(const ushort* __restrict__ qkvb, const ushort* __restrict__ vupT,
                 ushort* __restrict__ vexpT){
  const int h = blockIdx.y, t0 = blockIdx.x*64;
  const int tid = threadIdx.x, lane = tid&63, w = tid>>6;
  const int l15 = lane&15, quad = lane>>4;
  bf16x8 a[2][2], b[4][2];
  #pragma unroll
  for (int mt=0;mt<2;++mt)
    #pragma unroll
    for (int kk=0;kk<2;++kk)
      a[mt][kk] = *(const bf16x8*)(vupT + (size_t)h*D_*L_ + (w*32+mt*16+l15)*64 + kk*32 + quad*8);
  #pragma unroll
  for (int nt=0;nt<4;++nt)
    #pragma unroll
    for (int kk=0;kk<2;++kk)
      b[nt][kk] = *(const bf16x8*)(qkvb + (size_t)(t0+nt*16+l15)*NQ + 1088 + kk*32 + quad*8);
  floatx4 acc[2][4] = {};
  #pragma unroll
  for (int mt=0;mt<2;++mt)
    #pragma unroll
    for (int nt=0;nt<4;++nt)
      #pragma unroll
      for (int kk=0;kk<2;++kk)
        acc[mt][nt] = __builtin_amdgcn_mfma_f32_16x16x32_bf16(a[mt][kk], b[nt][kk], acc[mt][nt], 0,0,0);
  #pragma unroll
  for (int mt=0;mt<2;++mt)
    #pragma unroll
    for (int nt=0;nt<4;++nt)
      #pragma unroll
      for (int r=0;r<4;++r)
        vexpT[((size_t)h*D_ + w*32+mt*16+quad*4+r)*T_ + t0 + nt*16 + l15] = f2b(acc[mt][nt][r]);
}

// ---------------- flash attention, split-S, counted-vmcnt pipeline ---------
// (r12 version verbatim: KVBLK=64, single-buffered, disjoint K/V phases)
__global__ __launch_bounds__(256, 4)
void k_attn(const ushort* __restrict__ qkvb,   // [T][1152] bf16
            const float*  __restrict__ rsq,    // [T][16]  (scaled rowsums)
            const float*  __restrict__ rsk,    // [T]
            const ushort* __restrict__ vexpT,  // [16][128][T] bf16
            ushort*       __restrict__ ctx,    // [T][2048] bf16
            ushort*       __restrict__ partO,  // [16][24][4] swizzled 64x128 bf16
            float*        __restrict__ partML, // [16][24][4][64][2]
            int CH){
  __shared__ ushort Ks[64*64];      // 8KB, stride 64, XOR-swizzled chunks
  __shared__ ushort Vts[128*64];    // 16KB, stride 64, XOR-swizzled chunks
  __shared__ ushort Ps[4*16*64];    // 8KB, wave-private rows, chunk-swizzled
  const int h  = blockIdx.y;
  const int bxr = (int)gridDim.x - 1 - (int)blockIdx.x;   // heavy tiles first
  int qt, c;
  if (CH == 8){
    if (bxr < 8){ qt = bxr; c = 0; }
    else if (bxr < 24){ int u = bxr-8;  qt = 8  + (u>>1); c = u&1; }
    else if (bxr < 48){ int u = bxr-24; qt = 16 + u/3;    c = u - (u/3)*3; }
    else               { int u = bxr-48; qt = 24 + (u>>2); c = u&3; }
  } else { qt = bxr; c = 0; }
  const int nct = (qt + CH) / CH;
  const int stBeg = c*CH, stEnd = min(qt, stBeg + CH - 1);
  const int t0 = qt*64;
  const int tid = threadIdx.x, lane = tid & 63, w = tid >> 6;
  const int l15 = lane & 15, quad = lane >> 4;

  auto stageK = [&](int s0k){
    #pragma unroll
    for (int j=0;j<2;++j){ int cc = tid + j*256;
      int row = cc>>3, kc = ((cc&7) ^ (row&7))*8;
      glds16(qkvb + (size_t)(s0k + row)*NQ + 1024 + kc, &Ks[cc*8]); }
  };
  auto stageV = [&](int s0v){
    #pragma unroll
    for (int j=0;j<4;++j){ int cc = tid + j*256;
      int row = cc>>3, sc2 = ((cc&7) ^ (row&7))*8;
      glds16(vexpT + ((size_t)h*128 + row)*T_ + s0v + sc2, &Vts[cc*8]); }
  };

  const int qrow = t0 + w*16 + l15;
  const bf16x8 q0 = *(const bf16x8*)(qkvb + (size_t)qrow*NQ + h*64 + quad*8);
  const bf16x8 q1 = *(const bf16x8*)(qkvb + (size_t)qrow*NQ + h*64 + 32 + quad*8);
  const float rqv = rsq[(size_t)qrow*H_ + h] * 0.5f;      // already *isl*log2e

  float mrun = -INFINITY, lrun = 0.f;
  floatx4 o[8] = {};

  stageK(stBeg*64); stageV(stBeg*64);                // prologue

  for (int st=stBeg; st<=stEnd; ++st){
    const int s0 = st*64;
    const bool more = (st < stEnd);
    // ---- K(st) landed (V(st)'s 4 loads still in flight) ----
    asm volatile("s_waitcnt vmcnt(4)" ::: "memory");
    __builtin_amdgcn_s_barrier();
    __builtin_amdgcn_sched_barrier(0);
    // ---- S^T = K Q^T : lane owns q=l15, s=jt*16+quad*4+r ----
    floatx4 sT[4] = {};
    __builtin_amdgcn_s_setprio(1);
    #pragma unroll
    for (int jt=0;jt<4;++jt){
      const int srow = jt*16 + l15, sx = srow & 7;
      bf16x8 k0f = *(const bf16x8*)(&Ks[srow*64 + (quad^sx)*8]);
      sT[jt] = __builtin_amdgcn_mfma_f32_16x16x32_bf16(k0f, q0, sT[jt], 0,0,0);
      bf16x8 k1f = *(const bf16x8*)(&Ks[srow*64 + ((4+quad)^sx)*8]);
      sT[jt] = __builtin_amdgcn_mfma_f32_16x16x32_bf16(k1f, q1, sT[jt], 0,0,0);
    }
    __builtin_amdgcn_s_setprio(0);
    __builtin_amdgcn_sched_barrier(0);
    __builtin_amdgcn_s_barrier();                  // all K reads done
    if (more) stageK(s0 + 64);                     // K(t+1) under softmax+PV
    // ---- mask + rank-1 band (edge tiles only), in place in sT ----
    float mloc = -3.0e38f;
    if (st >= qt-1){
      #pragma unroll
      for (int jt=0;jt<4;++jt){
        const float4 rk4 = *(const float4*)(rsk + s0 + jt*16 + quad*4);  // broadcast
        #pragma unroll
        for (int r=0;r<4;++r){
          const int sg = s0 + jt*16 + quad*4 + r;
          const int dd = qrow - sg;
          float x = sT[jt][r];
          x = (dd <= 64) ? x + rqv*((const float*)&rk4)[r] : x;
          x = (dd < 0)   ? -3.0e38f : x;
          sT[jt][r] = x; mloc = fmaxf(mloc, x);
        }
      }
    } else {
      #pragma unroll
      for (int jt=0;jt<4;++jt)
        #pragma unroll
        for (int r=0;r<4;++r) mloc = fmaxf(mloc, sT[jt][r]);
    }
    mloc = fmaxf(mloc, __shfl_xor(mloc, 16));
    mloc = fmaxf(mloc, __shfl_xor(mloc, 32));
    // ---- defer-max (T13): keep old max unless it grew by >6 (log2 units) --
    const float mn = (mloc - mrun <= 6.0f) ? mrun : mloc;
    const float al = exp2f(mrun - mn);             // ==1.0 when deferred
    float ss = 0.f;
    #pragma unroll
    for (int jt=0;jt<4;++jt)
      #pragma unroll
      for (int r=0;r<4;++r){
        float p = exp2f(sT[jt][r]-mn); sT[jt][r] = p; ss += p;
      }
    ss += __shfl_xor(ss, 16); ss += __shfl_xor(ss, 32);
    lrun = lrun*al + ss; mrun = mn;
    // ---- P write (wave-private rows, chunk-swizzled; no barrier needed) ----
    #pragma unroll
    for (int jt=0;jt<4;++jt){
      unsigned p01, p23;
      asm volatile("v_cvt_pk_bf16_f32 %0, %1, %2" : "=v"(p01) : "v"(sT[jt][0]), "v"(sT[jt][1]));
      asm volatile("v_cvt_pk_bf16_f32 %0, %1, %2" : "=v"(p23) : "v"(sT[jt][2]), "v"(sT[jt][3]));
      const int chunk = 2*jt + (quad>>1);
      uint2 pw2; pw2.x = p01; pw2.y = p23;
      *(uint2*)(&Ps[(w*16 + l15)*64 + ((chunk ^ (l15&7))<<3) + (quad&1)*4]) = pw2;
    }
    // ---- rescale O rows (skip when no new max anywhere in wave) ----
    if (__any(al < 1.0f)){
      float alr[4];
      #pragma unroll
      for (int r=0;r<4;++r) alr[r] = __shfl(al, quad*4 + r);
      #pragma unroll
      for (int nt=0;nt<8;++nt){
        o[nt][0]*=alr[0]; o[nt][1]*=alr[1]; o[nt][2]*=alr[2]; o[nt][3]*=alr[3];
      }
    }
    // ---- V(st) landed (K(t+1)'s 2 loads still in flight) ----
    __builtin_amdgcn_sched_barrier(0);
    if (more) asm volatile("s_waitcnt vmcnt(2)" ::: "memory");
    else      asm volatile("s_waitcnt vmcnt(0)" ::: "memory");
    __builtin_amdgcn_s_barrier();
    __builtin_amdgcn_sched_barrier(0);
    // ---- O += P V ----
    __builtin_amdgcn_s_setprio(1);
    #pragma unroll
    for (int kks=0;kks<2;++kks){
      const int ch = kks*4 + quad;
      bf16x8 pf = *(const bf16x8*)(&Ps[(w*16 + l15)*64 + ((ch ^ (l15&7))<<3)]);
      #pragma unroll
      for (int nt=0;nt<8;++nt){
        const int vrow = nt*16 + l15, vx = vrow & 7;
        bf16x8 vf = *(const bf16x8*)(&Vts[vrow*64 + ((kks*4+quad)^vx)*8]);
        o[nt] = __builtin_amdgcn_mfma_f32_16x16x32_bf16(pf, vf, o[nt], 0,0,0);
      }
    }
    __builtin_amdgcn_s_setprio(0);
    __builtin_amdgcn_sched_barrier(0);
    if (more){
      __builtin_amdgcn_s_barrier();                // all V reads done
      stageV(s0 + 64);                             // V(t+1) under next QK+softmax
    }
  }
  // ---- epilogue ----
  const float linv = 1.f/lrun;
  float lr4[4];
  #pragma unroll
  for (int r=0;r<4;++r) lr4[r] = __shfl(linv, quad*4 + r);
  if (nct == 1){
    #pragma unroll
    for (int r=0;r<4;++r){
      const int row = t0 + w*16 + quad*4 + r;
      #pragma unroll
      for (int nt=0;nt<8;++nt)
        ctx[(size_t)row*E_ + h*D_ + nt*16 + l15] = f2b(o[nt][r]*lr4[r]);
    }
  } else {
    const int slot = (h*24 + (qt-8))*4 + c;
    ushort* po = partO + (size_t)slot*8192;            // swizzled [w][nt][r][lane]
    #pragma unroll
    for (int nt=0;nt<8;++nt)
      #pragma unroll
      for (int r=0;r<4;++r)
        po[((w*8+nt)*4+r)*64 + quad*16 + l15] = f2b(o[nt][r]*lr4[r]);  // 128B/instr
    if (quad == 0){
      float2 ml; ml.x = mrun; ml.y = lrun;
      ((float2*)partML)[(size_t)slot*64 + w*16 + l15] = ml;
    }
  }
}

// ---------------- merge partials -> ctx (qt >= 8) ----------------
__global__ __launch_bounds__(256)
void k_merge(const ushort* __restrict__ partO, const float* __restrict__ partML,
             ushort* __restrict__ ctx){
  const int h = blockIdx.y, qt = 8 + blockIdx.x;
  const int nct = (qt + 8) / 8;
  const int tid = threadIdx.x;
  const int rg = tid >> 2, d0 = (tid & 3)*32;
  const int w = rg >> 4, quad = (rg >> 2) & 3, rr = rg & 3;
  const int n0 = d0 >> 4;
  const int sbase = (h*24 + (qt-8))*4;
  float m[4], l[4], M = -INFINITY;
  for (int c=0;c<4;++c){
    if (c < nct){
      float2 v = ((const float2*)partML)[(size_t)(sbase+c)*64 + rg];
      m[c]=v.x; l[c]=v.y; M = fmaxf(M, v.x);
    }
  }
  float lt = 0.f, wgt[4];
  for (int c=0;c<4;++c){
    if (c < nct){ wgt[c] = exp2f(m[c]-M)*l[c]; lt += wgt[c]; }
  }
  const float inv = 1.f/lt;
  float acc[32];
  #pragma unroll
  for (int i=0;i<32;++i) acc[i]=0.f;
  for (int c=0;c<4;++c){
    if (c >= nct) break;
    const float sc = wgt[c]*inv;
    const ushort* po = partO + (size_t)(sbase+c)*8192;
    #pragma unroll
    for (int nn=0;nn<2;++nn){
      const ushort* p2 = po + ((w*8 + n0+nn)*4 + rr)*64 + quad*16;
      uint4 u  = *(const uint4*)p2;
      uint4 u2 = *(const uint4*)(p2 + 8);
      const unsigned int uu[8] = {u.x,u.y,u.z,u.w,u2.x,u2.y,u2.z,u2.w};
      #pragma unroll
      for (int q=0;q<8;++q){
        acc[nn*16+q*2]   += sc*blo(uu[q]);
        acc[nn*16+q*2+1] += sc*bhi(uu[q]);
      }
    }
  }
  ushort* dst = ctx + (size_t)(qt*64 + rg)*E_ + h*D_ + d0;
  #pragma unroll
  for (int k=0;k<8;++k){
    ushort4 ov; ov.x=f2b(acc[k*4]); ov.y=f2b(acc[k*4+1]);
    ov.z=f2b(acc[k*4+2]); ov.w=f2b(acc[k*4+3]);
    *(ushort4*)(dst + k*4) = ov;
  }
}

// ---------------- launch ----------------
extern "C" void kernel_launch(void* const* d_in, const int* in_sizes, int n_in,
                              void* d_out, int out_size, void* d_ws, size_t ws_size,
                              hipStream_t stream) {
  const float* hs  = (const float*)d_in[0];
  const float* Wq  = (const float*)d_in[1];
  const float* Wk  = (const float*)d_in[2];
  const float* Wv  = (const float*)d_in[3];
  const float* q2l = (const float*)d_in[4];
  const float* vup = (const float*)d_in[5];
  const float* Wo  = (const float*)d_in[6];
  float* out = (float*)d_out;
  char* ws = (char*)d_ws;

  // workspace layout (bytes) — round-6 proven layout
  ushort* hsb   = (ushort*)(ws + 0);           // [2048][2048] bf16
  ushort* Wqkvb = (ushort*)(ws + 8388608);     // [1152][2048] bf16 (ql|k|v)
  ushort* Wob   = (ushort*)(ws + 13107200);    // [2048][2048] bf16
  ushort* qkvb  = (ushort*)(ws + 21495808);    // [2048][1152] bf16
  ushort* vupT  = (ushort*)(ws + 26214400);    // [16][128][64] bf16
  float*  rsqp  = (float*) (ws + 26476544);    // [2048][16]
  float*  rskp  = (float*) (ws + 26607616);    // [2048]
  ushort* vexpT = (ushort*)(ws + 26615808);    // [16][128][2048] bf16
  ushort* ctxb  = (ushort*)(ws + 35004416);    // [2048][2048] bf16
  ushort* partO = (ushort*)(ws + 43393024);    // [16][24][4] x 8192 bf16 (swizzled)
  float*  partML= (float*) (ws + 68558848);    // [16][24][4][64][2]
  const size_t NEED = 69345280;
  const int CH = (ws_size >= NEED) ? 8 : 32;

  // 1) fused prep: bf16 conversions + Wql fold + vupT transpose (one launch)
  k_prep<<<8976, 256, 0, stream>>>(hs, hsb, Wo, Wob,
                                   Wk, Wqkvb + (size_t)1024*E_,
                                   Wv, Wqkvb + (size_t)1088*E_,
                                   Wq, q2l, Wqkvb, vup, vupT);

  // 2) fused q_latent|k|v GEMM + rowsum epilogue -> qkvb, rsq, rsk
  gemm_glds2<2,2,true,true><<<dim3(18,32), 256, 0, stream>>>(
      hsb, Wqkvb, nullptr, qkvb, rsqp, rskp, T_, NQ, E_, 0.18033688f);

  // 3) V_exp^T via MFMA
  k_vexp_mfma<<<dim3(32,16), 256, 0, stream>>>(qkvb, vupT, vexpT);

  // 4) flash attention (split-S, r12 pipeline) -> ctx / partials
  k_attn<<<dim3(CH==8 ? 80 : 32, 16), 256, 0, stream>>>(
      qkvb, rsqp, rskp, vexpT, ctxb, partO, partML, CH);

  // 5) merge partials
  if (CH == 8)
    k_merge<<<dim3(24,16), 256, 0, stream>>>(partO, partML, ctxb);

  // 6) out = ctx @ Wo^T (fp32 to d_out): 64x128 tiles, BK=64, 512 blocks
  gemm_glds2<2,4,false,false><<<dim3(16,32), 256, 0, stream>>>(
      ctxb, Wob, out, nullptr, nullptr, nullptr, T_, E_, E_, 1.0f);
}

// Round 11
// 234.023 us; speedup vs baseline: 1.3842x; 1.0370x over previous
//
#include <hip/hip_runtime.h>

// RA_MLA_Attention — MI355X (gfx950). Round 17.
// B=1, T=2048, E=2048, H=16, D=128, L=64, RA_WINDOW=64, RA_ALPHA=0.5
//
// Round-17 changes (k_prep only; rest byte-identical to r16 = 242.7us champ):
//   * r16 profile exposed k_prep at ~52us steady-state: the wql-fold branch
//     ran 1024 waves on 1024 SIMDs (1/SIMD) -- a 128-iter serial load loop
//     with zero latency hiding (VALU 8%, occ 17%, ~750cyc/iter).
//   * Fix: acc[32]->acc[8]; 1024 blocks x 256 thr = 4 waves/SIMD (Wq
//     re-read 8x = 128MB, L3-absorbed). wql blocks dispatched FIRST so the
//     streaming-convert blocks backfill around the long wql waves; the
//     kernel tail is the parallel streaming drain, not the wql straggler.

#define T_ 2048
#define E_ 2048
#define H_ 16
#define D_ 128
#define L_ 64
#define NQ 1152            // fused qkv GEMM N (1024 ql | 64 k | 64 v)

typedef float  floatx4 __attribute__((ext_vector_type(4)));
typedef __bf16 bf16x8  __attribute__((ext_vector_type(8)));

__device__ __forceinline__ ushort f2b(float x){           // fp32 -> bf16 bits, RNE
  unsigned int u = __float_as_uint(x);
  u = (u + 0x7fffu + ((u >> 16) & 1u)) >> 16;
  return (ushort)u;
}
__device__ __forceinline__ float blo(unsigned int u){ return __uint_as_float(u << 16); }
__device__ __forceinline__ float bhi(unsigned int u){ return __uint_as_float(u & 0xffff0000u); }

__device__ __forceinline__ void glds16(const ushort* g, ushort* l){
#if __has_builtin(__builtin_amdgcn_global_load_lds)
  __builtin_amdgcn_global_load_lds((const __attribute__((address_space(1))) void*)g,
                                   (__attribute__((address_space(3))) void*)l, 16, 0, 0);
#else
  *(uint4*)l = *(const uint4*)g;
#endif
}

// ---------------- fused prep: wql-fold + vupT + f2b4 (one launch) ----------
// Block order: [0,1024) wql (slow waves, launched first), [1024,1040) vupT,
// [1040,9488) streaming conversions (backfill + fast drain).
__global__ __launch_bounds__(256)
void k_prep(const float* __restrict__ hs, ushort* __restrict__ hsb,
            const float* __restrict__ Wo, ushort* __restrict__ Wob,
            const float* __restrict__ Wk, ushort* __restrict__ Wkb,
            const float* __restrict__ Wv, ushort* __restrict__ Wvb,
            const float* __restrict__ Wq, const float* __restrict__ q2l,
            ushort* __restrict__ Wql,
            const float* __restrict__ vup, ushort* __restrict__ vupT){
  const int bid = blockIdx.x;
  if (bid < 1024){
    // ---- fold q_to_latent into Wq: Wql[(h,l),e], 8 l's per block ----
    const int h = bid >> 6, lo = (bid >> 3) & 7, ex = bid & 7;
    const int e = ex*256 + (int)threadIdx.x;
    const float* qb = q2l + (size_t)h*D_*L_ + lo*8;
    float acc[8];
    #pragma unroll
    for (int i=0;i<8;++i) acc[i]=0.f;
    #pragma unroll 2
    for (int d=0; d<128; ++d){
      float wv = Wq[(size_t)(h*128+d)*E_ + e];
      #pragma unroll
      for (int i=0;i<8;++i) acc[i] += wv*qb[(size_t)d*64 + i];
    }
    #pragma unroll
    for (int i=0;i<8;++i) Wql[(size_t)(h*64 + lo*8 + i)*E_ + e] = f2b(acc[i]);
  } else if (bid < 1040){
    // ---- vupT[h][d][l] = vup[h][l][d] ----
    const int h = bid - 1024, tid = threadIdx.x;
    for (int idx = tid; idx < L_*D_; idx += 256){
      int l = idx >> 7, d = idx & 127;
      vupT[(size_t)h*D_*L_ + d*64 + l] = f2b(vup[(size_t)h*L_*D_ + idx]);
    }
  } else {
    // ---- fp32 -> bf16 conversions ----
    const int b2 = bid - 1040;
    const float* src; ushort* dst; int base;
    if (b2 < 4096){ src=hs; dst=hsb; base=b2; }
    else if (b2 < 8192){ src=Wo; dst=Wob; base=b2-4096; }
    else if (b2 < 8320){ src=Wk; dst=Wkb; base=b2-8192; }
    else { src=Wv; dst=Wvb; base=b2-8320; }
    int i = (base*256 + (int)threadIdx.x)*4;
    float4 v = *(const float4*)(src + i);
    ushort4 o; o.x=f2b(v.x); o.y=f2b(v.y); o.z=f2b(v.z); o.w=f2b(v.w);
    *(ushort4*)(dst + i) = o;
  }
}

// ---------------- BK=64 GEMM: C[M,N] = A[M,K] @ B[N,K]^T --------------------
// 4 waves 2x2; BM=32*MT, BN=32*NT. LDS rows stride 64 ushort (128B) with
// 16B-chunk XOR swizzle (glds SOURCE-permuted; LDS writes stay linear).
// Bijective XCD chunk swizzle. OB16: bf16 out with col-block scale.
// RS: rowsum epilogue (qkv only, BN=64): rsq for ql tiles, rsk for k tile.
template<int MT,int NT,bool OB16,bool RS>
__global__ __launch_bounds__(256)
void gemm_glds2(const ushort* __restrict__ A, const ushort* __restrict__ B,
                float* __restrict__ Cf, ushort* __restrict__ Cb,
                float* __restrict__ rsq, float* __restrict__ rsk,
                int M, int N, int K, float scale){
  constexpr int BM = 32*MT, BN = 32*NT;
  constexpr int IA = BM/32, IB = BN/32;     // glds16 per thread per K-step
  __shared__ ushort As[BM*64];
  __shared__ ushort Bs[BN*64];
  const int tid = threadIdx.x, lane = tid&63, wv = tid>>6;
  const int wm = wv & 1, wn = wv >> 1;
  const int l15 = lane&15, quad = lane>>4;
  const int nbx = (int)gridDim.x, nwg = nbx*(int)gridDim.y;  // nwg % 8 == 0
  int bid = (int)blockIdx.y*nbx + (int)blockIdx.x;
  bid = (bid & 7)*(nwg >> 3) + (bid >> 3);
  const int m0 = (bid / nbx)*BM, n0 = (bid % nbx)*BN;
  const float sc = (n0 < 1024) ? scale : 1.0f;     // qkv: ql cols scaled
  floatx4 acc[MT][NT] = {};
  for (int k0=0; k0<K; k0+=64){
    __syncthreads();
    #pragma unroll
    for (int j=0;j<IA;++j){
      int cc = j*256 + tid; int row = cc>>3, kc = ((cc&7)^(row&7))*8;
      glds16(A + (size_t)(m0+row)*K + k0 + kc, &As[cc*8]);
    }
    #pragma unroll
    for (int j=0;j<IB;++j){
      int cc = j*256 + tid; int row = cc>>3, kc = ((cc&7)^(row&7))*8;
      glds16(B + (size_t)(n0+row)*K + k0 + kc, &Bs[cc*8]);
    }
    __syncthreads();
    #pragma unroll
    for (int kk=0;kk<2;++kk){
      bf16x8 af[MT], bfr[NT];
      #pragma unroll
      for (int mi=0;mi<MT;++mi){
        const int r = wm*MT*16 + mi*16 + l15;
        af[mi] = *(const bf16x8*)(&As[r*64 + (((kk*4+quad)^(r&7))<<3)]);
      }
      #pragma unroll
      for (int ni=0;ni<NT;++ni){
        const int r = wn*NT*16 + ni*16 + l15;
        bfr[ni] = *(const bf16x8*)(&Bs[r*64 + (((kk*4+quad)^(r&7))<<3)]);
      }
      #pragma unroll
      for (int mi=0;mi<MT;++mi)
        #pragma unroll
        for (int ni=0;ni<NT;++ni)
          acc[mi][ni] = __builtin_amdgcn_mfma_f32_16x16x32_bf16(af[mi], bfr[ni], acc[mi][ni], 0,0,0);
    }
  }
  #pragma unroll
  for (int mi=0;mi<MT;++mi){
    const int rb = m0 + wm*MT*16 + mi*16 + quad*4;
    #pragma unroll
    for (int ni=0;ni<NT;++ni){
      const int col = n0 + wn*NT*16 + ni*16 + l15;
      #pragma unroll
      for (int r=0;r<4;++r){
        if constexpr (OB16) Cb[(size_t)(rb+r)*N + col] = f2b(acc[mi][ni][r]*sc);
        else                Cf[(size_t)(rb+r)*N + col] = acc[mi][ni][r];
      }
    }
  }
  if constexpr (RS){
    // rowsums from fp32 acc: ql tiles (n0<1024) -> rsq[t][h]; k tile
    // (n0==1024) -> rsk[t]; v tile (n0==1088) skipped.
    if (n0 != 1088){
      float rp[MT][4];
      #pragma unroll
      for (int mi=0;mi<MT;++mi)
        #pragma unroll
        for (int r=0;r<4;++r){
          float v = 0.f;
          #pragma unroll
          for (int ni=0;ni<NT;++ni) v += acc[mi][ni][r];
          #pragma unroll
          for (int off=1;off<16;off<<=1) v += __shfl_xor(v, off);
          rp[mi][r] = v;
        }
      float* Asf = (float*)As;
      __syncthreads();                    // all waves done with As reads
      if (l15 == 0){
        #pragma unroll
        for (int mi=0;mi<MT;++mi)
          #pragma unroll
          for (int r=0;r<4;++r)
            Asf[wn*BM + wm*MT*16 + mi*16 + quad*4 + r] = rp[mi][r];
      }
      __syncthreads();
      if (tid < BM){
        float total = Asf[tid] + Asf[BM + tid];
        if (n0 < 1024) rsq[(size_t)(m0+tid)*H_ + (n0>>6)] = total*scale;
        else           rsk[m0+tid] = total;
      }
    }
  }
}

// ---------------- V_exp^T[h][d][t] via MFMA, register-only ----------------
__global__ __launch_bounds__(256)
void k_vexp_mfma(const ushort* __restrict__ qkvb, const ushort* __restrict__ vupT,
                 ushort* __restrict__ vexpT){
  const int h = blockIdx.y, t0 = blockIdx.x*64;
  const int tid = threadIdx.x, lane = tid&63, w = tid>>6;
  const int l15 = lane&15, quad = lane>>4;
  bf16x8 a[2][2], b[4][2];
  #pragma unroll
  for (int mt=0;mt<2;++mt)
    #pragma unroll
    for (int kk=0;kk<2;++kk)
      a[mt][kk] = *(const bf16x8*)(vupT + (size_t)h*D_*L_ + (w*32+mt*16+l15)*64 + kk*32 + quad*8);
  #pragma unroll
  for (int nt=0;nt<4;++nt)
    #pragma unroll
    for (int kk=0;kk<2;++kk)
      b[nt][kk] = *(const bf16x8*)(qkvb + (size_t)(t0+nt*16+l15)*NQ + 1088 + kk*32 + quad*8);
  floatx4 acc[2][4] = {};
  #pragma unroll
  for (int mt=0;mt<2;++mt)
    #pragma unroll
    for (int nt=0;nt<4;++nt)
      #pragma unroll
      for (int kk=0;kk<2;++kk)
        acc[mt][nt] = __builtin_amdgcn_mfma_f32_16x16x32_bf16(a[mt][kk], b[nt][kk], acc[mt][nt], 0,0,0);
  #pragma unroll
  for (int mt=0;mt<2;++mt)
    #pragma unroll
    for (int nt=0;nt<4;++nt)
      #pragma unroll
      for (int r=0;r<4;++r)
        vexpT[((size_t)h*D_ + w*32+mt*16+quad*4+r)*T_ + t0 + nt*16 + l15] = f2b(acc[mt][nt][r]);
}

// ---------------- flash attention, split-S, counted-vmcnt pipeline ---------
// (r12 version verbatim: KVBLK=64, single-buffered, disjoint K/V phases)
__global__ __launch_bounds__(256, 4)
void k_attn(const ushort* __restrict__ qkvb,   // [T][1152] bf16
            const float*  __restrict__ rsq,    // [T][16]  (scaled rowsums)
            const float*  __restrict__ rsk,    // [T]
            const ushort* __restrict__ vexpT,  // [16][128][T] bf16
            ushort*       __restrict__ ctx,    // [T][2048] bf16
            ushort*       __restrict__ partO,  // [16][24][4] swizzled 64x128 bf16
            float*        __restrict__ partML, // [16][24][4][64][2]
            int CH){
  __shared__ ushort Ks[64*64];      // 8KB, stride 64, XOR-swizzled chunks
  __shared__ ushort Vts[128*64];    // 16KB, stride 64, XOR-swizzled chunks
  __shared__ ushort Ps[4*16*64];    // 8KB, wave-private rows, chunk-swizzled
  const int h  = blockIdx.y;
  const int bxr = (int)gridDim.x - 1 - (int)blockIdx.x;   // heavy tiles first
  int qt, c;
  if (CH == 8){
    if (bxr < 8){ qt = bxr; c = 0; }
    else if (bxr < 24){ int u = bxr-8;  qt = 8  + (u>>1); c = u&1; }
    else if (bxr < 48){ int u = bxr-24; qt = 16 + u/3;    c = u - (u/3)*3; }
    else               { int u = bxr-48; qt = 24 + (u>>2); c = u&3; }
  } else { qt = bxr; c = 0; }
  const int nct = (qt + CH) / CH;
  const int stBeg = c*CH, stEnd = min(qt, stBeg + CH - 1);
  const int t0 = qt*64;
  const int tid = threadIdx.x, lane = tid & 63, w = tid >> 6;
  const int l15 = lane & 15, quad = lane >> 4;

  auto stageK = [&](int s0k){
    #pragma unroll
    for (int j=0;j<2;++j){ int cc = tid + j*256;
      int row = cc>>3, kc = ((cc&7) ^ (row&7))*8;
      glds16(qkvb + (size_t)(s0k + row)*NQ + 1024 + kc, &Ks[cc*8]); }
  };
  auto stageV = [&](int s0v){
    #pragma unroll
    for (int j=0;j<4;++j){ int cc = tid + j*256;
      int row = cc>>3, sc2 = ((cc&7) ^ (row&7))*8;
      glds16(vexpT + ((size_t)h*128 + row)*T_ + s0v + sc2, &Vts[cc*8]); }
  };

  const int qrow = t0 + w*16 + l15;
  const bf16x8 q0 = *(const bf16x8*)(qkvb + (size_t)qrow*NQ + h*64 + quad*8);
  const bf16x8 q1 = *(const bf16x8*)(qkvb + (size_t)qrow*NQ + h*64 + 32 + quad*8);
  const float rqv = rsq[(size_t)qrow*H_ + h] * 0.5f;      // already *isl*log2e

  float mrun = -INFINITY, lrun = 0.f;
  floatx4 o[8] = {};

  stageK(stBeg*64); stageV(stBeg*64);                // prologue

  for (int st=stBeg; st<=stEnd; ++st){
    const int s0 = st*64;
    const bool more = (st < stEnd);
    // ---- K(st) landed (V(st)'s 4 loads still in flight) ----
    asm volatile("s_waitcnt vmcnt(4)" ::: "memory");
    __builtin_amdgcn_s_barrier();
    __builtin_amdgcn_sched_barrier(0);
    // ---- S^T = K Q^T : lane owns q=l15, s=jt*16+quad*4+r ----
    floatx4 sT[4] = {};
    __builtin_amdgcn_s_setprio(1);
    #pragma unroll
    for (int jt=0;jt<4;++jt){
      const int srow = jt*16 + l15, sx = srow & 7;
      bf16x8 k0f = *(const bf16x8*)(&Ks[srow*64 + (quad^sx)*8]);
      sT[jt] = __builtin_amdgcn_mfma_f32_16x16x32_bf16(k0f, q0, sT[jt], 0,0,0);
      bf16x8 k1f = *(const bf16x8*)(&Ks[srow*64 + ((4+quad)^sx)*8]);
      sT[jt] = __builtin_amdgcn_mfma_f32_16x16x32_bf16(k1f, q1, sT[jt], 0,0,0);
    }
    __builtin_amdgcn_s_setprio(0);
    __builtin_amdgcn_sched_barrier(0);
    __builtin_amdgcn_s_barrier();                  // all K reads done
    if (more) stageK(s0 + 64);                     // K(t+1) under softmax+PV
    // ---- mask + rank-1 band (edge tiles only), in place in sT ----
    float mloc = -3.0e38f;
    if (st >= qt-1){
      #pragma unroll
      for (int jt=0;jt<4;++jt){
        const float4 rk4 = *(const float4*)(rsk + s0 + jt*16 + quad*4);  // broadcast
        #pragma unroll
        for (int r=0;r<4;++r){
          const int sg = s0 + jt*16 + quad*4 + r;
          const int dd = qrow - sg;
          float x = sT[jt][r];
          x = (dd <= 64) ? x + rqv*((const float*)&rk4)[r] : x;
          x = (dd < 0)   ? -3.0e38f : x;
          sT[jt][r] = x; mloc = fmaxf(mloc, x);
        }
      }
    } else {
      #pragma unroll
      for (int jt=0;jt<4;++jt)
        #pragma unroll
        for (int r=0;r<4;++r) mloc = fmaxf(mloc, sT[jt][r]);
    }
    mloc = fmaxf(mloc, __shfl_xor(mloc, 16));
    mloc = fmaxf(mloc, __shfl_xor(mloc, 32));
    // ---- defer-max (T13): keep old max unless it grew by >6 (log2 units) --
    const float mn = (mloc - mrun <= 6.0f) ? mrun : mloc;
    const float al = exp2f(mrun - mn);             // ==1.0 when deferred
    float ss = 0.f;
    #pragma unroll
    for (int jt=0;jt<4;++jt)
      #pragma unroll
      for (int r=0;r<4;++r){
        float p = exp2f(sT[jt][r]-mn); sT[jt][r] = p; ss += p;
      }
    ss += __shfl_xor(ss, 16); ss += __shfl_xor(ss, 32);
    lrun = lrun*al + ss; mrun = mn;
    // ---- P write (wave-private rows, chunk-swizzled; no barrier needed) ----
    #pragma unroll
    for (int jt=0;jt<4;++jt){
      unsigned p01, p23;
      asm volatile("v_cvt_pk_bf16_f32 %0, %1, %2" : "=v"(p01) : "v"(sT[jt][0]), "v"(sT[jt][1]));
      asm volatile("v_cvt_pk_bf16_f32 %0, %1, %2" : "=v"(p23) : "v"(sT[jt][2]), "v"(sT[jt][3]));
      const int chunk = 2*jt + (quad>>1);
      uint2 pw2; pw2.x = p01; pw2.y = p23;
      *(uint2*)(&Ps[(w*16 + l15)*64 + ((chunk ^ (l15&7))<<3) + (quad&1)*4]) = pw2;
    }
    // ---- rescale O rows (skip when no new max anywhere in wave) ----
    if (__any(al < 1.0f)){
      float alr[4];
      #pragma unroll
      for (int r=0;r<4;++r) alr[r] = __shfl(al, quad*4 + r);
      #pragma unroll
      for (int nt=0;nt<8;++nt){
        o[nt][0]*=alr[0]; o[nt][1]*=alr[1]; o[nt][2]*=alr[2]; o[nt][3]*=alr[3];
      }
    }
    // ---- V(st) landed (K(t+1)'s 2 loads still in flight) ----
    __builtin_amdgcn_sched_barrier(0);
    if (more) asm volatile("s_waitcnt vmcnt(2)" ::: "memory");
    else      asm volatile("s_waitcnt vmcnt(0)" ::: "memory");
    __builtin_amdgcn_s_barrier();
    __builtin_amdgcn_sched_barrier(0);
    // ---- O += P V ----
    __builtin_amdgcn_s_setprio(1);
    #pragma unroll
    for (int kks=0;kks<2;++kks){
      const int ch = kks*4 + quad;
      bf16x8 pf = *(const bf16x8*)(&Ps[(w*16 + l15)*64 + ((ch ^ (l15&7))<<3)]);
      #pragma unroll
      for (int nt=0;nt<8;++nt){
        const int vrow = nt*16 + l15, vx = vrow & 7;
        bf16x8 vf = *(const bf16x8*)(&Vts[vrow*64 + ((kks*4+quad)^vx)*8]);
        o[nt] = __builtin_amdgcn_mfma_f32_16x16x32_bf16(pf, vf, o[nt], 0,0,0);
      }
    }
    __builtin_amdgcn_s_setprio(0);
    __builtin_amdgcn_sched_barrier(0);
    if (more){
      __builtin_amdgcn_s_barrier();                // all V reads done
      stageV(s0 + 64);                             // V(t+1) under next QK+softmax
    }
  }
  // ---- epilogue ----
  const float linv = 1.f/lrun;
  float lr4[4];
  #pragma unroll
  for (int r=0;r<4;++r) lr4[r] = __shfl(linv, quad*4 + r);
  if (nct == 1){
    #pragma unroll
    for (int r=0;r<4;++r){
      const int row = t0 + w*16 + quad*4 + r;
      #pragma unroll
      for (int nt=0;nt<8;++nt)
        ctx[(size_t)row*E_ + h*D_ + nt*16 + l15] = f2b(o[nt][r]*lr4[r]);
    }
  } else {
    const int slot = (h*24 + (qt-8))*4 + c;
    ushort* po = partO + (size_t)slot*8192;            // swizzled [w][nt][r][lane]
    #pragma unroll
    for (int nt=0;nt<8;++nt)
      #pragma unroll
      for (int r=0;r<4;++r)
        po[((w*8+nt)*4+r)*64 + quad*16 + l15] = f2b(o[nt][r]*lr4[r]);  // 128B/instr
    if (quad == 0){
      float2 ml; ml.x = mrun; ml.y = lrun;
      ((float2*)partML)[(size_t)slot*64 + w*16 + l15] = ml;
    }
  }
}

// ---------------- merge partials -> ctx (qt >= 8) ----------------
__global__ __launch_bounds__(256)
void k_merge(const ushort* __restrict__ partO, const float* __restrict__ partML,
             ushort* __restrict__ ctx){
  const int h = blockIdx.y, qt = 8 + blockIdx.x;
  const int nct = (qt + 8) / 8;
  const int tid = threadIdx.x;
  const int rg = tid >> 2, d0 = (tid & 3)*32;
  const int w = rg >> 4, quad = (rg >> 2) & 3, rr = rg & 3;
  const int n0 = d0 >> 4;
  const int sbase = (h*24 + (qt-8))*4;
  float m[4], l[4], M = -INFINITY;
  for (int c=0;c<4;++c){
    if (c < nct){
      float2 v = ((const float2*)partML)[(size_t)(sbase+c)*64 + rg];
      m[c]=v.x; l[c]=v.y; M = fmaxf(M, v.x);
    }
  }
  float lt = 0.f, wgt[4];
  for (int c=0;c<4;++c){
    if (c < nct){ wgt[c] = exp2f(m[c]-M)*l[c]; lt += wgt[c]; }
  }
  const float inv = 1.f/lt;
  float acc[32];
  #pragma unroll
  for (int i=0;i<32;++i) acc[i]=0.f;
  for (int c=0;c<4;++c){
    if (c >= nct) break;
    const float sc = wgt[c]*inv;
    const ushort* po = partO + (size_t)(sbase+c)*8192;
    #pragma unroll
    for (int nn=0;nn<2;++nn){
      const ushort* p2 = po + ((w*8 + n0+nn)*4 + rr)*64 + quad*16;
      uint4 u  = *(const uint4*)p2;
      uint4 u2 = *(const uint4*)(p2 + 8);
      const unsigned int uu[8] = {u.x,u.y,u.z,u.w,u2.x,u2.y,u2.z,u2.w};
      #pragma unroll
      for (int q=0;q<8;++q){
        acc[nn*16+q*2]   += sc*blo(uu[q]);
        acc[nn*16+q*2+1] += sc*bhi(uu[q]);
      }
    }
  }
  ushort* dst = ctx + (size_t)(qt*64 + rg)*E_ + h*D_ + d0;
  #pragma unroll
  for (int k=0;k<8;++k){
    ushort4 ov; ov.x=f2b(acc[k*4]); ov.y=f2b(acc[k*4+1]);
    ov.z=f2b(acc[k*4+2]); ov.w=f2b(acc[k*4+3]);
    *(ushort4*)(dst + k*4) = ov;
  }
}

// ---------------- launch ----------------
extern "C" void kernel_launch(void* const* d_in, const int* in_sizes, int n_in,
                              void* d_out, int out_size, void* d_ws, size_t ws_size,
                              hipStream_t stream) {
  const float* hs  = (const float*)d_in[0];
  const float* Wq  = (const float*)d_in[1];
  const float* Wk  = (const float*)d_in[2];
  const float* Wv  = (const float*)d_in[3];
  const float* q2l = (const float*)d_in[4];
  const float* vup = (const float*)d_in[5];
  const float* Wo  = (const float*)d_in[6];
  float* out = (float*)d_out;
  char* ws = (char*)d_ws;

  // workspace layout (bytes) — round-6 proven layout
  ushort* hsb   = (ushort*)(ws + 0);           // [2048][2048] bf16
  ushort* Wqkvb = (ushort*)(ws + 8388608);     // [1152][2048] bf16 (ql|k|v)
  ushort* Wob   = (ushort*)(ws + 13107200);    // [2048][2048] bf16
  ushort* qkvb  = (ushort*)(ws + 21495808);    // [2048][1152] bf16
  ushort* vupT  = (ushort*)(ws + 26214400);    // [16][128][64] bf16
  float*  rsqp  = (float*) (ws + 26476544);    // [2048][16]
  float*  rskp  = (float*) (ws + 26607616);    // [2048]
  ushort* vexpT = (ushort*)(ws + 26615808);    // [16][128][2048] bf16
  ushort* ctxb  = (ushort*)(ws + 35004416);    // [2048][2048] bf16
  ushort* partO = (ushort*)(ws + 43393024);    // [16][24][4] x 8192 bf16 (swizzled)
  float*  partML= (float*) (ws + 68558848);    // [16][24][4][64][2]
  const size_t NEED = 69345280;
  const int CH = (ws_size >= NEED) ? 8 : 32;

  // 1) fused prep: Wql fold (first) + vupT + bf16 conversions (one launch)
  k_prep<<<9488, 256, 0, stream>>>(hs, hsb, Wo, Wob,
                                   Wk, Wqkvb + (size_t)1024*E_,
                                   Wv, Wqkvb + (size_t)1088*E_,
                                   Wq, q2l, Wqkvb, vup, vupT);

  // 2) fused q_latent|k|v GEMM + rowsum epilogue -> qkvb, rsq, rsk
  gemm_glds2<2,2,true,true><<<dim3(18,32), 256, 0, stream>>>(
      hsb, Wqkvb, nullptr, qkvb, rsqp, rskp, T_, NQ, E_, 0.18033688f);

  // 3) V_exp^T via MFMA
  k_vexp_mfma<<<dim3(32,16), 256, 0, stream>>>(qkvb, vupT, vexpT);

  // 4) flash attention (split-S, r12 pipeline) -> ctx / partials
  k_attn<<<dim3(CH==8 ? 80 : 32, 16), 256, 0, stream>>>(
      qkvb, rsqp, rskp, vexpT, ctxb, partO, partML, CH);

  // 5) merge partials
  if (CH == 8)
    k_merge<<<dim3(24,16), 256, 0, stream>>>(partO, partML, ctxb);

  // 6) out = ctx @ Wo^T (fp32 to d_out): 64x128 tiles, BK=64, 512 blocks
  gemm_glds2<2,4,false,false><<<dim3(16,32), 256, 0, stream>>>(
      ctxb, Wob, out, nullptr, nullptr, nullptr, T_, E_, E_, 1.0f);
}